// Round 4
// baseline (497.761 us; speedup 1.0000x reference)
//
#include <hip/hip_runtime.h>
#include <hip/hip_bf16.h>

#define N_NODES 100000
#define N_EDGES 1600000

#define NT 391                               // row buckets of 256 rows
#define NB1 128                              // partition blocks
#define CHUNK ((N_EDGES + NB1 - 1) / NB1)    // 12500 edges per block
#define L3_BLOCKS 2000                       // pool-partial blocks (100000/5/10)

// ---------------- bf16 helpers (manual RNE) ----------------
__device__ __forceinline__ float b2f(unsigned short h) {
    return __uint_as_float(((unsigned)h) << 16);
}
__device__ __forceinline__ unsigned short f2bf(float f) {
    unsigned u = __float_as_uint(f);
    u += 0x7FFFu + ((u >> 16) & 1u);
    return (unsigned short)(u >> 16);
}

// ---------------- CSR build: contention-free two-pass bucket partition ----------------

__global__ __launch_bounds__(256) void k_phist(const int* __restrict__ row, int* __restrict__ blkhist) {
    __shared__ int h[NT];
    int b = blockIdx.x, t = threadIdx.x;
    for (int i = t; i < NT; i += 256) h[i] = 0;
    __syncthreads();
    int s = b * CHUNK, e = min(s + CHUNK, N_EDGES);
    for (int i = s + t; i < e; i += 256) atomicAdd(&h[row[i] >> 8], 1);
    __syncthreads();
    for (int i = t; i < NT; i += 256) blkhist[b * NT + i] = h[i];   // b-major
}

__global__ __launch_bounds__(512) void k_pscan(int* __restrict__ blkhist, int* __restrict__ base,
                                               int* __restrict__ cnt, int* __restrict__ row_ptr) {
    __shared__ int s[512];
    int j = threadIdx.x;
    int tot = 0;
    if (j < NT) {
        for (int b = 0; b < NB1; ++b) {                  // coalesced across j
            int v = blkhist[b * NT + j];
            blkhist[b * NT + j] = tot;
            tot += v;
        }
    }
    s[j] = (j < NT) ? tot : 0;
    __syncthreads();
    for (int st = 1; st < 512; st <<= 1) {
        int u = (j >= st) ? s[j - st] : 0;
        __syncthreads();
        s[j] += u;
        __syncthreads();
    }
    if (j < NT) {
        int bs = s[j] - tot;                             // exclusive bucket base
        base[j] = bs;
        cnt[j] = tot;
        for (int b = 0; b < NB1; ++b) blkhist[b * NT + j] += bs;
    }
    if (j == 0) row_ptr[N_NODES] = N_EDGES;
}

__global__ __launch_bounds__(256) void k_pscatter(const int* __restrict__ row, const int* __restrict__ col,
                                                  const float* __restrict__ val,
                                                  const int* __restrict__ blkhist, int2* __restrict__ part) {
    __shared__ int cur[NT];
    int b = blockIdx.x, t = threadIdx.x;
    for (int i = t; i < NT; i += 256) cur[i] = blkhist[b * NT + i];
    __syncthreads();
    int s = b * CHUNK, e = min(s + CHUNK, N_EDGES);
    for (int i = s + t; i < e; i += 256) {
        int r = row[i];
        int j = r >> 8;
        int p = atomicAdd(&cur[j], 1);
        part[p] = make_int2(((r & 255) << 24) | col[i], __float_as_int(val[i]));
    }
}

__global__ __launch_bounds__(256) void k_sort(const int2* __restrict__ part, const int* __restrict__ cnt,
                                              const int* __restrict__ base, int* __restrict__ row_ptr,
                                              int2* __restrict__ csr) {
    __shared__ int hist[256];
    __shared__ int cur[256];
    int b = blockIdx.x, t = threadIdx.x;
    int n = cnt[b];
    int bb = base[b];
    const int2* sl = part + bb;
    hist[t] = 0;
    __syncthreads();
    for (int i = t; i < n; i += 256) atomicAdd(&hist[((unsigned)sl[i].x) >> 24], 1);
    __syncthreads();
    int v = hist[t];
    for (int st = 1; st < 256; st <<= 1) {
        int u = (t >= st) ? hist[t - st] : 0;
        __syncthreads();
        hist[t] += u;
        __syncthreads();
    }
    cur[t] = hist[t] - v;
    int grow = b * 256 + t;
    if (grow < N_NODES) row_ptr[grow] = bb + cur[t];
    __syncthreads();
    for (int i = t; i < n; i += 256) {
        int2 e = sl[i];
        int rl = ((unsigned)e.x) >> 24;
        int p = atomicAdd(&cur[rl], 1);
        csr[bb + p] = make_int2(e.x & 0xFFFFFF, e.y);
    }
}

// ---------------- GEMM1: x[N,256] @ W1[256,32] -> support bf16 [N,32] ----------------
// W slice in registers, float4 LDS reads of x.
__global__ __launch_bounds__(256) void k_gemm1(const float* __restrict__ x, const float* __restrict__ W,
                                               unsigned short* __restrict__ out) {
    __shared__ float xs[64][68];
    int tid = threadIdx.x;
    int bn = blockIdx.x * 64;
    int tn = tid & 31;        // node pair
    int to = tid >> 5;        // out quad
    float acc[2][4] = {};
    for (int kc = 0; kc < 4; ++kc) {
        int k0 = kc * 64;
        #pragma unroll
        for (int i = 0; i < 4; ++i) {
            int idx = i * 256 + tid;
            int n = idx >> 4;
            int k4 = (idx & 15) * 4;
            float4 v = make_float4(0.f, 0.f, 0.f, 0.f);
            if (bn + n < N_NODES)
                v = *reinterpret_cast<const float4*>(&x[(size_t)(bn + n) * 256 + k0 + k4]);
            *reinterpret_cast<float4*>(&xs[n][k4]) = v;
        }
        __syncthreads();
        #pragma unroll
        for (int sc = 0; sc < 4; ++sc) {
            int ks = k0 + sc * 16;
            float4 wr[16];
            #pragma unroll
            for (int j = 0; j < 16; ++j)
                wr[j] = *reinterpret_cast<const float4*>(&W[(size_t)(ks + j) * 32 + 4 * to]);
            #pragma unroll
            for (int j4 = 0; j4 < 4; ++j4) {
                float4 a0 = *reinterpret_cast<float4*>(&xs[2 * tn][sc * 16 + j4 * 4]);
                float4 a1 = *reinterpret_cast<float4*>(&xs[2 * tn + 1][sc * 16 + j4 * 4]);
                float4 w0 = wr[j4 * 4 + 0], w1 = wr[j4 * 4 + 1], w2 = wr[j4 * 4 + 2], w3 = wr[j4 * 4 + 3];
                acc[0][0] += a0.x * w0.x + a0.y * w1.x + a0.z * w2.x + a0.w * w3.x;
                acc[0][1] += a0.x * w0.y + a0.y * w1.y + a0.z * w2.y + a0.w * w3.y;
                acc[0][2] += a0.x * w0.z + a0.y * w1.z + a0.z * w2.z + a0.w * w3.z;
                acc[0][3] += a0.x * w0.w + a0.y * w1.w + a0.z * w2.w + a0.w * w3.w;
                acc[1][0] += a1.x * w0.x + a1.y * w1.x + a1.z * w2.x + a1.w * w3.x;
                acc[1][1] += a1.x * w0.y + a1.y * w1.y + a1.z * w2.y + a1.w * w3.y;
                acc[1][2] += a1.x * w0.z + a1.y * w1.z + a1.z * w2.z + a1.w * w3.z;
                acc[1][3] += a1.x * w0.w + a1.y * w1.w + a1.z * w2.w + a1.w * w3.w;
            }
        }
        __syncthreads();
    }
    #pragma unroll
    for (int i = 0; i < 2; ++i) {
        int n = bn + 2 * tn + i;
        if (n < N_NODES) {
            ushort4 r;
            r.x = f2bf(acc[i][0]); r.y = f2bf(acc[i][1]);
            r.z = f2bf(acc[i][2]); r.w = f2bf(acc[i][3]);
            *reinterpret_cast<ushort4*>(&out[(size_t)n * 32 + 4 * to]) = r;
        }
    }
}

// ---------------- SpMM layer1: gather bf16 support, +bias relu -> h1 bf16 ----------------
__global__ __launch_bounds__(256) void k_spmm1(const int* __restrict__ rp, const int2* __restrict__ csr,
                                               const unsigned short* __restrict__ sup,
                                               const float* __restrict__ bias,
                                               unsigned short* __restrict__ out) {
    int gid = blockIdx.x * 256 + threadIdx.x;
    int n = gid >> 5;
    int f = gid & 31;
    if (n >= N_NODES) return;
    int e0 = rp[n], e1 = rp[n + 1];
    float acc0 = 0.f, acc1 = 0.f;
    int e = e0;
    for (; e + 1 < e1; e += 2) {
        int2 a = csr[e], b = csr[e + 1];
        acc0 += __int_as_float(a.y) * b2f(sup[(size_t)a.x * 32 + f]);
        acc1 += __int_as_float(b.y) * b2f(sup[(size_t)b.x * 32 + f]);
    }
    if (e < e1) {
        int2 a = csr[e];
        acc0 += __int_as_float(a.y) * b2f(sup[(size_t)a.x * 32 + f]);
    }
    float acc = fmaxf(acc0 + acc1 + bias[f], 0.f);
    out[(size_t)n * 32 + f] = f2bf(acc);
}

// ---------------- layer2 fused: g2 = spmm(h1) ; h2 = relu(g2@W2+b2) bf16 ----------------
__global__ __launch_bounds__(256) void k_l2fused(const int* __restrict__ rp, const int2* __restrict__ csr,
                                                 const unsigned short* __restrict__ h1,
                                                 const float* __restrict__ W2, const float* __restrict__ b2,
                                                 unsigned short* __restrict__ h2) {
    __shared__ float w2s[32 * 48];
    __shared__ float b2s[48];
    __shared__ float g2s[8][33];
    int tid = threadIdx.x;
    for (int i = tid; i < 32 * 48; i += 256) w2s[i] = W2[i];
    if (tid < 48) b2s[tid] = b2[tid];
    int n0 = blockIdx.x * 8;
    int ln = tid >> 5, f = tid & 31;
    int n = n0 + ln;
    float acc0 = 0.f, acc1 = 0.f;
    {
        int e0 = rp[n], e1 = rp[n + 1];
        int e = e0;
        for (; e + 1 < e1; e += 2) {
            int2 a = csr[e], b = csr[e + 1];
            acc0 += __int_as_float(a.y) * b2f(h1[(size_t)a.x * 32 + f]);
            acc1 += __int_as_float(b.y) * b2f(h1[(size_t)b.x * 32 + f]);
        }
        if (e < e1) {
            int2 a = csr[e];
            acc0 += __int_as_float(a.y) * b2f(h1[(size_t)a.x * 32 + f]);
        }
    }
    g2s[ln][f] = acc0 + acc1;
    __syncthreads();
    for (int idx = tid; idx < 8 * 48; idx += 256) {
        int r = idx / 48;
        int m = idx - 48 * r;
        float a = b2s[m];
        const float* g = g2s[r];
        #pragma unroll
        for (int k = 0; k < 32; ++k) a += g[k] * w2s[k * 48 + m];
        h2[(size_t)(n0 + r) * 48 + m] = f2bf(fmaxf(a, 0.f));
    }
}

// ---------------- layer3 fused: g3 = spmm(h2); h3=relu(g3@W3+b3); pool partial ----------------
__global__ __launch_bounds__(256) void k_l3fused(const int* __restrict__ rp, const int2* __restrict__ csr,
                                                 const unsigned short* __restrict__ h2,
                                                 const float* __restrict__ W3, const float* __restrict__ b3,
                                                 float* __restrict__ poolpart) {
    __shared__ float w3s[48 * 64];
    __shared__ float b3s[64];
    __shared__ float g3s[5][49];
    __shared__ float red[256];
    int tid = threadIdx.x;
    for (int i = tid; i < 48 * 64; i += 256) w3s[i] = W3[i];
    if (tid < 64) b3s[tid] = b3[tid];
    int r5 = tid / 48;            // gather row 0..4 (tid<240)
    int f = tid - 48 * r5;
    int m = tid & 63;
    float poolacc = 0.f;
    for (int g = blockIdx.x; g < N_NODES / 5; g += L3_BLOCKS) {
        __syncthreads();          // protect g3s from previous dense reads
        if (tid < 240) {
            int n = g * 5 + r5;
            int e0 = rp[n], e1 = rp[n + 1];
            float acc0 = 0.f, acc1 = 0.f;
            int e = e0;
            for (; e + 1 < e1; e += 2) {
                int2 a = csr[e], b = csr[e + 1];
                acc0 += __int_as_float(a.y) * b2f(h2[(size_t)a.x * 48 + f]);
                acc1 += __int_as_float(b.y) * b2f(h2[(size_t)b.x * 48 + f]);
            }
            if (e < e1) {
                int2 a = csr[e];
                acc0 += __int_as_float(a.y) * b2f(h2[(size_t)a.x * 48 + f]);
            }
            g3s[r5][f] = acc0 + acc1;
        }
        __syncthreads();
        // dense: 5 rows x 64 outs = 320 -> iter0: r=tid>>6 (0..3); iter1: tid<64 -> r=4
        {
            int r = tid >> 6;
            float a = b3s[m];
            const float* gg = g3s[r];
            #pragma unroll
            for (int k = 0; k < 48; ++k) a += gg[k] * w3s[k * 64 + m];
            poolacc += fmaxf(a, 0.f);
        }
        if (tid < 64) {
            float a = b3s[m];
            const float* gg = g3s[4];
            #pragma unroll
            for (int k = 0; k < 48; ++k) a += gg[k] * w3s[k * 64 + m];
            poolacc += fmaxf(a, 0.f);
        }
    }
    __syncthreads();
    red[tid] = poolacc;
    __syncthreads();
    if (tid < 64) {
        float s = red[tid] + red[tid + 64] + red[tid + 128] + red[tid + 192];
        poolpart[(size_t)blockIdx.x * 64 + tid] = s;
    }
}

// ---------------- head: reduce poolpart -> mean -> FC1+relu -> FC2 -> softmax ----------------
__global__ __launch_bounds__(256) void k_head(const float* __restrict__ poolpart,
                                              const float* __restrict__ fc1W, const float* __restrict__ fc1b,
                                              const float* __restrict__ fc2W, const float* __restrict__ fc2b,
                                              float* __restrict__ out) {
    __shared__ float red[256];
    __shared__ float pl[64];
    __shared__ float z[32];
    __shared__ float lg[2];
    int tid = threadIdx.x;
    int m = tid & 63, j0 = tid >> 6;
    float s = 0.f;
    for (int j = j0; j < L3_BLOCKS; j += 4) s += poolpart[(size_t)j * 64 + m];
    red[tid] = s;
    __syncthreads();
    if (tid < 64) pl[tid] = (red[tid] + red[tid + 64] + red[tid + 128] + red[tid + 192]) * (1.0f / (float)N_NODES);
    __syncthreads();
    if (tid < 32) {
        float a = fc1b[tid];
        for (int o = 0; o < 64; ++o) a += pl[o] * fc1W[o * 32 + tid];
        z[tid] = fmaxf(a, 0.f);
    }
    __syncthreads();
    if (tid < 2) {
        float l = fc2b[tid];
        for (int j = 0; j < 32; ++j) l += z[j] * fc2W[j * 2 + tid];
        lg[tid] = l;
    }
    __syncthreads();
    if (tid == 0) {
        float mx = fmaxf(lg[0], lg[1]);
        float e0 = __expf(lg[0] - mx), e1 = __expf(lg[1] - mx);
        float ss = e0 + e1;
        out[0] = e0 / ss;
        out[1] = e1 / ss;
    }
}

// ---------------- launch ----------------

extern "C" void kernel_launch(void* const* d_in, const int* in_sizes, int n_in,
                              void* d_out, int out_size, void* d_ws, size_t ws_size,
                              hipStream_t stream) {
    const float* x    = (const float*)d_in[0];
    const int*   row  = (const int*)d_in[1];
    const int*   col  = (const int*)d_in[2];
    const float* val  = (const float*)d_in[3];
    const float* W1   = (const float*)d_in[4];
    const float* b1   = (const float*)d_in[5];
    const float* W2   = (const float*)d_in[6];
    const float* b2   = (const float*)d_in[7];
    const float* W3   = (const float*)d_in[8];
    const float* b3   = (const float*)d_in[9];
    const float* fc1W = (const float*)d_in[10];
    const float* fc1b = (const float*)d_in[11];
    const float* fc2W = (const float*)d_in[12];
    const float* fc2b = (const float*)d_in[13];
    float* out = (float*)d_out;

    char* wsb = (char*)d_ws;
    size_t off = 0;
    auto alloc = [&](size_t bytes) {
        void* p = wsb + off;
        off += (bytes + 255) / 256 * 256;
        return p;
    };
    int*   blkhist  = (int*)alloc((size_t)NT * NB1 * 4);
    int*   base     = (int*)alloc((size_t)NT * 4);
    int*   cnt      = (int*)alloc((size_t)NT * 4);
    int*   row_ptr  = (int*)alloc((size_t)(N_NODES + 1) * 4);
    int2*  part     = (int2*)alloc((size_t)N_EDGES * 8);
    int2*  csr      = (int2*)alloc((size_t)N_EDGES * 8);
    unsigned short* sup = (unsigned short*)alloc((size_t)N_NODES * 32 * 2);
    unsigned short* h1  = (unsigned short*)alloc((size_t)N_NODES * 32 * 2);
    unsigned short* h2  = (unsigned short*)alloc((size_t)N_NODES * 48 * 2);
    float* poolpart = (float*)alloc((size_t)L3_BLOCKS * 64 * 4);

    // CSR build (no global atomics)
    k_phist<<<NB1, 256, 0, stream>>>(row, blkhist);
    k_pscan<<<1, 512, 0, stream>>>(blkhist, base, cnt, row_ptr);
    k_pscatter<<<NB1, 256, 0, stream>>>(row, col, val, blkhist, part);
    k_sort<<<NT, 256, 0, stream>>>(part, cnt, base, row_ptr, csr);

    // layer 1
    k_gemm1<<<(N_NODES + 63) / 64, 256, 0, stream>>>(x, W1, sup);
    k_spmm1<<<(N_NODES * 32) / 256, 256, 0, stream>>>(row_ptr, csr, sup, b1, h1);
    // layer 2 fused
    k_l2fused<<<N_NODES / 8, 256, 0, stream>>>(row_ptr, csr, h1, W2, b2, h2);
    // layer 3 fused + pool partials
    k_l3fused<<<L3_BLOCKS, 256, 0, stream>>>(row_ptr, csr, h2, W3, b3, poolpart);
    // head
    k_head<<<1, 256, 0, stream>>>(poolpart, fc1W, fc1b, fc2W, fc2b, out);
}

// Round 5
// 384.484 us; speedup vs baseline: 1.2946x; 1.2946x over previous
//
#include <hip/hip_runtime.h>
#include <hip/hip_bf16.h>

#define N_NODES 100000
#define N_EDGES 1600000

#define NT 391                               // row buckets of 256 rows
#define NB1 128                              // partition blocks
#define CHUNK ((N_EDGES + NB1 - 1) / NB1)    // 12500 edges per block
#define L3_BLOCKS 2000                       // pool-partial blocks

// ---------------- bf16 helpers (manual RNE) ----------------
__device__ __forceinline__ float b2f(unsigned short h) {
    return __uint_as_float(((unsigned)h) << 16);
}
__device__ __forceinline__ unsigned short f2bf(float f) {
    unsigned u = __float_as_uint(f);
    u += 0x7FFFu + ((u >> 16) & 1u);
    return (unsigned short)(u >> 16);
}

// ---------------- CSR build: contention-free two-pass bucket partition ----------------

__global__ __launch_bounds__(256) void k_phist(const int* __restrict__ row, int* __restrict__ blkhist) {
    __shared__ int h[NT];
    int b = blockIdx.x, t = threadIdx.x;
    for (int i = t; i < NT; i += 256) h[i] = 0;
    __syncthreads();
    int s = b * CHUNK, e = min(s + CHUNK, N_EDGES);
    for (int i = s + t; i < e; i += 256) atomicAdd(&h[row[i] >> 8], 1);
    __syncthreads();
    for (int i = t; i < NT; i += 256) blkhist[b * NT + i] = h[i];   // b-major
}

__global__ __launch_bounds__(512) void k_pscan(int* __restrict__ blkhist, int* __restrict__ base,
                                               int* __restrict__ cnt, int* __restrict__ row_ptr) {
    __shared__ int s[512];
    int j = threadIdx.x;
    int tot = 0;
    if (j < NT) {
        for (int b = 0; b < NB1; ++b) {                  // coalesced across j
            int v = blkhist[b * NT + j];
            blkhist[b * NT + j] = tot;
            tot += v;
        }
    }
    s[j] = (j < NT) ? tot : 0;
    __syncthreads();
    for (int st = 1; st < 512; st <<= 1) {
        int u = (j >= st) ? s[j - st] : 0;
        __syncthreads();
        s[j] += u;
        __syncthreads();
    }
    if (j < NT) {
        int bs = s[j] - tot;                             // exclusive bucket base
        base[j] = bs;
        cnt[j] = tot;
        for (int b = 0; b < NB1; ++b) blkhist[b * NT + j] += bs;
    }
    if (j == 0) row_ptr[N_NODES] = N_EDGES;
}

__global__ __launch_bounds__(256) void k_pscatter(const int* __restrict__ row, const int* __restrict__ col,
                                                  const float* __restrict__ val,
                                                  const int* __restrict__ blkhist, int2* __restrict__ part) {
    __shared__ int cur[NT];
    int b = blockIdx.x, t = threadIdx.x;
    for (int i = t; i < NT; i += 256) cur[i] = blkhist[b * NT + i];
    __syncthreads();
    int s = b * CHUNK, e = min(s + CHUNK, N_EDGES);
    for (int i = s + t; i < e; i += 256) {
        int r = row[i];
        int j = r >> 8;
        int p = atomicAdd(&cur[j], 1);
        part[p] = make_int2(((r & 255) << 24) | col[i], __float_as_int(val[i]));
    }
}

__global__ __launch_bounds__(256) void k_sort(const int2* __restrict__ part, const int* __restrict__ cnt,
                                              const int* __restrict__ base, int* __restrict__ row_ptr,
                                              int2* __restrict__ csr) {
    __shared__ int hist[256];
    __shared__ int cur[256];
    int b = blockIdx.x, t = threadIdx.x;
    int n = cnt[b];
    int bb = base[b];
    const int2* sl = part + bb;
    hist[t] = 0;
    __syncthreads();
    for (int i = t; i < n; i += 256) atomicAdd(&hist[((unsigned)sl[i].x) >> 24], 1);
    __syncthreads();
    int v = hist[t];
    for (int st = 1; st < 256; st <<= 1) {
        int u = (t >= st) ? hist[t - st] : 0;
        __syncthreads();
        hist[t] += u;
        __syncthreads();
    }
    cur[t] = hist[t] - v;
    int grow = b * 256 + t;
    if (grow < N_NODES) row_ptr[grow] = bb + cur[t];
    __syncthreads();
    for (int i = t; i < n; i += 256) {
        int2 e = sl[i];
        int rl = ((unsigned)e.x) >> 24;
        int p = atomicAdd(&cur[rl], 1);
        csr[bb + p] = make_int2(e.x & 0xFFFFFF, e.y);
    }
}

// ---------------- GEMM1: x[N,256] @ W1[256,32] -> support bf16 [N,32] ----------------
__global__ __launch_bounds__(256) void k_gemm1(const float* __restrict__ x, const float* __restrict__ W,
                                               unsigned short* __restrict__ out) {
    __shared__ float xs[64][68];
    int tid = threadIdx.x;
    int bn = blockIdx.x * 64;
    int tn = tid & 31;        // node pair
    int to = tid >> 5;        // out quad
    float acc[2][4] = {};
    for (int kc = 0; kc < 4; ++kc) {
        int k0 = kc * 64;
        #pragma unroll
        for (int i = 0; i < 4; ++i) {
            int idx = i * 256 + tid;
            int n = idx >> 4;
            int k4 = (idx & 15) * 4;
            float4 v = make_float4(0.f, 0.f, 0.f, 0.f);
            if (bn + n < N_NODES)
                v = *reinterpret_cast<const float4*>(&x[(size_t)(bn + n) * 256 + k0 + k4]);
            *reinterpret_cast<float4*>(&xs[n][k4]) = v;
        }
        __syncthreads();
        #pragma unroll
        for (int sc = 0; sc < 4; ++sc) {
            int ks = k0 + sc * 16;
            float4 wr[16];
            #pragma unroll
            for (int j = 0; j < 16; ++j)
                wr[j] = *reinterpret_cast<const float4*>(&W[(size_t)(ks + j) * 32 + 4 * to]);
            #pragma unroll
            for (int j4 = 0; j4 < 4; ++j4) {
                float4 a0 = *reinterpret_cast<float4*>(&xs[2 * tn][sc * 16 + j4 * 4]);
                float4 a1 = *reinterpret_cast<float4*>(&xs[2 * tn + 1][sc * 16 + j4 * 4]);
                float4 w0 = wr[j4 * 4 + 0], w1 = wr[j4 * 4 + 1], w2 = wr[j4 * 4 + 2], w3 = wr[j4 * 4 + 3];
                acc[0][0] += a0.x * w0.x + a0.y * w1.x + a0.z * w2.x + a0.w * w3.x;
                acc[0][1] += a0.x * w0.y + a0.y * w1.y + a0.z * w2.y + a0.w * w3.y;
                acc[0][2] += a0.x * w0.z + a0.y * w1.z + a0.z * w2.z + a0.w * w3.z;
                acc[0][3] += a0.x * w0.w + a0.y * w1.w + a0.z * w2.w + a0.w * w3.w;
                acc[1][0] += a1.x * w0.x + a1.y * w1.x + a1.z * w2.x + a1.w * w3.x;
                acc[1][1] += a1.x * w0.y + a1.y * w1.y + a1.z * w2.y + a1.w * w3.y;
                acc[1][2] += a1.x * w0.z + a1.y * w1.z + a1.z * w2.z + a1.w * w3.z;
                acc[1][3] += a1.x * w0.w + a1.y * w1.w + a1.z * w2.w + a1.w * w3.w;
            }
        }
        __syncthreads();
    }
    #pragma unroll
    for (int i = 0; i < 2; ++i) {
        int n = bn + 2 * tn + i;
        if (n < N_NODES) {
            ushort4 r;
            r.x = f2bf(acc[i][0]); r.y = f2bf(acc[i][1]);
            r.z = f2bf(acc[i][2]); r.w = f2bf(acc[i][3]);
            *reinterpret_cast<ushort4*>(&out[(size_t)n * 32 + 4 * to]) = r;
        }
    }
}

// ---------------- SpMM layer1 ----------------
__global__ __launch_bounds__(256) void k_spmm1(const int* __restrict__ rp, const int2* __restrict__ csr,
                                               const unsigned short* __restrict__ sup,
                                               const float* __restrict__ bias,
                                               unsigned short* __restrict__ out) {
    int gid = blockIdx.x * 256 + threadIdx.x;
    int n = gid >> 5;
    int f = gid & 31;
    if (n >= N_NODES) return;
    int e0 = rp[n], e1 = rp[n + 1];
    float acc0 = 0.f, acc1 = 0.f;
    int e = e0;
    for (; e + 1 < e1; e += 2) {
        int2 a = csr[e], b = csr[e + 1];
        acc0 += __int_as_float(a.y) * b2f(sup[(size_t)a.x * 32 + f]);
        acc1 += __int_as_float(b.y) * b2f(sup[(size_t)b.x * 32 + f]);
    }
    if (e < e1) {
        int2 a = csr[e];
        acc0 += __int_as_float(a.y) * b2f(sup[(size_t)a.x * 32 + f]);
    }
    float acc = fmaxf(acc0 + acc1 + bias[f], 0.f);
    out[(size_t)n * 32 + f] = f2bf(acc);
}

// ---------------- layer2 fused: g2 = spmm(h1) ; h2 = relu(g2@W2+b2) bf16 ----------------
__global__ __launch_bounds__(256) void k_l2fused(const int* __restrict__ rp, const int2* __restrict__ csr,
                                                 const unsigned short* __restrict__ h1,
                                                 const float* __restrict__ W2, const float* __restrict__ b2,
                                                 unsigned short* __restrict__ h2) {
    __shared__ float w2s[32 * 48];
    __shared__ float b2s[48];
    __shared__ float g2s[8][33];
    int tid = threadIdx.x;
    for (int i = tid; i < 32 * 48; i += 256) w2s[i] = W2[i];
    if (tid < 48) b2s[tid] = b2[tid];
    int n0 = blockIdx.x * 8;
    int ln = tid >> 5, f = tid & 31;
    int n = n0 + ln;
    float acc0 = 0.f, acc1 = 0.f;
    {
        int e0 = rp[n], e1 = rp[n + 1];
        int e = e0;
        for (; e + 1 < e1; e += 2) {
            int2 a = csr[e], b = csr[e + 1];
            acc0 += __int_as_float(a.y) * b2f(h1[(size_t)a.x * 32 + f]);
            acc1 += __int_as_float(b.y) * b2f(h1[(size_t)b.x * 32 + f]);
        }
        if (e < e1) {
            int2 a = csr[e];
            acc0 += __int_as_float(a.y) * b2f(h1[(size_t)a.x * 32 + f]);
        }
    }
    g2s[ln][f] = acc0 + acc1;
    __syncthreads();
    for (int idx = tid; idx < 8 * 48; idx += 256) {
        int r = idx / 48;
        int m = idx - 48 * r;
        float a = b2s[m];
        const float* g = g2s[r];
        #pragma unroll
        for (int k = 0; k < 32; ++k) a += g[k] * w2s[k * 48 + m];
        h2[(size_t)(n0 + r) * 48 + m] = f2bf(fmaxf(a, 0.f));
    }
}

// ---------------- layer3 fused: g3 = spmm(h2); h3=relu(g3@W3+b3); pool partial ----------------
__global__ __launch_bounds__(256) void k_l3fused(const int* __restrict__ rp, const int2* __restrict__ csr,
                                                 const unsigned short* __restrict__ h2,
                                                 const float* __restrict__ W3, const float* __restrict__ b3,
                                                 float* __restrict__ poolpart) {
    __shared__ float w3s[48 * 64];
    __shared__ float b3s[64];
    __shared__ float g3s[5][49];
    __shared__ float red[256];
    int tid = threadIdx.x;
    for (int i = tid; i < 48 * 64; i += 256) w3s[i] = W3[i];
    if (tid < 64) b3s[tid] = b3[tid];
    int r5 = tid / 48;            // gather row 0..4 (tid<240)
    int f = tid - 48 * r5;
    int m = tid & 63;
    float poolacc = 0.f;
    for (int g = blockIdx.x; g < N_NODES / 5; g += L3_BLOCKS) {
        __syncthreads();          // protect g3s from previous dense reads
        if (tid < 240) {
            int n = g * 5 + r5;
            int e0 = rp[n], e1 = rp[n + 1];
            float acc0 = 0.f, acc1 = 0.f;
            int e = e0;
            for (; e + 1 < e1; e += 2) {
                int2 a = csr[e], b = csr[e + 1];
                acc0 += __int_as_float(a.y) * b2f(h2[(size_t)a.x * 48 + f]);
                acc1 += __int_as_float(b.y) * b2f(h2[(size_t)b.x * 48 + f]);
            }
            if (e < e1) {
                int2 a = csr[e];
                acc0 += __int_as_float(a.y) * b2f(h2[(size_t)a.x * 48 + f]);
            }
            g3s[r5][f] = acc0 + acc1;
        }
        __syncthreads();
        {
            int r = tid >> 6;
            float a = b3s[m];
            const float* gg = g3s[r];
            #pragma unroll
            for (int k = 0; k < 48; ++k) a += gg[k] * w3s[k * 64 + m];
            poolacc += fmaxf(a, 0.f);
        }
        if (tid < 64) {
            float a = b3s[m];
            const float* gg = g3s[4];
            #pragma unroll
            for (int k = 0; k < 48; ++k) a += gg[k] * w3s[k * 64 + m];
            poolacc += fmaxf(a, 0.f);
        }
    }
    __syncthreads();
    red[tid] = poolacc;
    __syncthreads();
    if (tid < 64) {
        float s = red[tid] + red[tid + 64] + red[tid + 128] + red[tid + 192];
        poolpart[(size_t)blockIdx.x * 64 + tid] = s;
    }
}

// ---------------- pool reduce: poolpart[2000][64] -> pool[64] (64 blocks) ----------------
__global__ __launch_bounds__(256) void k_preduce(const float* __restrict__ poolpart,
                                                 float* __restrict__ pool) {
    __shared__ float red[256];
    int b = blockIdx.x, t = threadIdx.x;
    float s = 0.f;
    for (int j = t; j < L3_BLOCKS; j += 256) s += poolpart[(size_t)j * 64 + b];
    red[t] = s;
    __syncthreads();
    for (int st = 128; st > 0; st >>= 1) {
        if (t < st) red[t] += red[t + st];
        __syncthreads();
    }
    if (t == 0) pool[b] = red[0];
}

// ---------------- head: mean -> FC1+relu -> FC2 -> softmax (tiny) ----------------
__global__ __launch_bounds__(64) void k_head(const float* __restrict__ pool,
                                             const float* __restrict__ fc1W, const float* __restrict__ fc1b,
                                             const float* __restrict__ fc2W, const float* __restrict__ fc2b,
                                             float* __restrict__ out) {
    __shared__ float pl[64];
    __shared__ float z[32];
    __shared__ float lg[2];
    int t = threadIdx.x;
    pl[t] = pool[t] * (1.0f / (float)N_NODES);
    __syncthreads();
    if (t < 32) {
        float a = fc1b[t];
        #pragma unroll
        for (int o = 0; o < 64; ++o) a += pl[o] * fc1W[o * 32 + t];
        z[t] = fmaxf(a, 0.f);
    }
    __syncthreads();
    if (t < 2) {
        float l = fc2b[t];
        #pragma unroll
        for (int j = 0; j < 32; ++j) l += z[j] * fc2W[j * 2 + t];
        lg[t] = l;
    }
    __syncthreads();
    if (t == 0) {
        float mx = fmaxf(lg[0], lg[1]);
        float e0 = __expf(lg[0] - mx), e1 = __expf(lg[1] - mx);
        float ss = e0 + e1;
        out[0] = e0 / ss;
        out[1] = e1 / ss;
    }
}

// ---------------- launch ----------------

extern "C" void kernel_launch(void* const* d_in, const int* in_sizes, int n_in,
                              void* d_out, int out_size, void* d_ws, size_t ws_size,
                              hipStream_t stream) {
    const float* x    = (const float*)d_in[0];
    const int*   row  = (const int*)d_in[1];
    const int*   col  = (const int*)d_in[2];
    const float* val  = (const float*)d_in[3];
    const float* W1   = (const float*)d_in[4];
    const float* b1   = (const float*)d_in[5];
    const float* W2   = (const float*)d_in[6];
    const float* b2   = (const float*)d_in[7];
    const float* W3   = (const float*)d_in[8];
    const float* b3   = (const float*)d_in[9];
    const float* fc1W = (const float*)d_in[10];
    const float* fc1b = (const float*)d_in[11];
    const float* fc2W = (const float*)d_in[12];
    const float* fc2b = (const float*)d_in[13];
    float* out = (float*)d_out;

    char* wsb = (char*)d_ws;
    size_t off = 0;
    auto alloc = [&](size_t bytes) {
        void* p = wsb + off;
        off += (bytes + 255) / 256 * 256;
        return p;
    };
    int*   blkhist  = (int*)alloc((size_t)NT * NB1 * 4);
    int*   base     = (int*)alloc((size_t)NT * 4);
    int*   cnt      = (int*)alloc((size_t)NT * 4);
    int*   row_ptr  = (int*)alloc((size_t)(N_NODES + 1) * 4);
    int2*  part     = (int2*)alloc((size_t)N_EDGES * 8);
    int2*  csr      = (int2*)alloc((size_t)N_EDGES * 8);
    unsigned short* sup = (unsigned short*)alloc((size_t)N_NODES * 32 * 2);
    unsigned short* h1  = (unsigned short*)alloc((size_t)N_NODES * 32 * 2);
    unsigned short* h2  = (unsigned short*)alloc((size_t)N_NODES * 48 * 2);
    float* poolpart = (float*)alloc((size_t)L3_BLOCKS * 64 * 4);
    float* pool     = (float*)alloc(64 * 4);

    // CSR build (no global atomics)
    k_phist<<<NB1, 256, 0, stream>>>(row, blkhist);
    k_pscan<<<1, 512, 0, stream>>>(blkhist, base, cnt, row_ptr);
    k_pscatter<<<NB1, 256, 0, stream>>>(row, col, val, blkhist, part);
    k_sort<<<NT, 256, 0, stream>>>(part, cnt, base, row_ptr, csr);

    // layer 1
    k_gemm1<<<(N_NODES + 63) / 64, 256, 0, stream>>>(x, W1, sup);
    k_spmm1<<<(N_NODES * 32) / 256, 256, 0, stream>>>(row_ptr, csr, sup, b1, h1);
    // layer 2 fused
    k_l2fused<<<N_NODES / 8, 256, 0, stream>>>(row_ptr, csr, h1, W2, b2, h2);
    // layer 3 fused + pool partials
    k_l3fused<<<L3_BLOCKS, 256, 0, stream>>>(row_ptr, csr, h2, W3, b3, poolpart);
    // pool reduce + head
    k_preduce<<<64, 256, 0, stream>>>(poolpart, pool);
    k_head<<<1, 64, 0, stream>>>(pool, fc1W, fc1b, fc2W, fc2b, out);
}

// Round 6
// 307.689 us; speedup vs baseline: 1.6177x; 1.2496x over previous
//
#include <hip/hip_runtime.h>
#include <hip/hip_bf16.h>

#define N_NODES 100000
#define N_EDGES 1600000

#define NT 391                               // row buckets of 256 rows
#define NB1 128                              // partition blocks
#define CHUNK ((N_EDGES + NB1 - 1) / NB1)    // 12500 edges per block
#define L3_BLOCKS 2000                       // pool-partial blocks

// ---------------- bf16 helpers (manual RNE) ----------------
__device__ __forceinline__ float b2f(unsigned short h) {
    return __uint_as_float(((unsigned)h) << 16);
}
__device__ __forceinline__ unsigned short f2bf(float f) {
    unsigned u = __float_as_uint(f);
    u += 0x7FFFu + ((u >> 16) & 1u);
    return (unsigned short)(u >> 16);
}

// ---------------- CSR build: contention-free two-pass bucket partition ----------------

__global__ __launch_bounds__(256) void k_phist(const int* __restrict__ row, int* __restrict__ blkhist) {
    __shared__ int h[NT];
    int b = blockIdx.x, t = threadIdx.x;
    for (int i = t; i < NT; i += 256) h[i] = 0;
    __syncthreads();
    int s = b * CHUNK, e = min(s + CHUNK, N_EDGES);
    for (int i = s + t; i < e; i += 256) atomicAdd(&h[row[i] >> 8], 1);
    __syncthreads();
    for (int i = t; i < NT; i += 256) blkhist[b * NT + i] = h[i];   // b-major
}

__global__ __launch_bounds__(512) void k_pscan(int* __restrict__ blkhist, int* __restrict__ base,
                                               int* __restrict__ cnt, int* __restrict__ row_ptr) {
    __shared__ int s[512];
    int j = threadIdx.x;
    int tot = 0;
    if (j < NT) {
        for (int b = 0; b < NB1; ++b) {                  // coalesced across j
            int v = blkhist[b * NT + j];
            blkhist[b * NT + j] = tot;
            tot += v;
        }
    }
    s[j] = (j < NT) ? tot : 0;
    __syncthreads();
    for (int st = 1; st < 512; st <<= 1) {
        int u = (j >= st) ? s[j - st] : 0;
        __syncthreads();
        s[j] += u;
        __syncthreads();
    }
    if (j < NT) {
        int bs = s[j] - tot;                             // exclusive bucket base
        base[j] = bs;
        cnt[j] = tot;
        for (int b = 0; b < NB1; ++b) blkhist[b * NT + j] += bs;
    }
    if (j == 0) row_ptr[N_NODES] = N_EDGES;
}

__global__ __launch_bounds__(256) void k_pscatter(const int* __restrict__ row, const int* __restrict__ col,
                                                  const float* __restrict__ val,
                                                  const int* __restrict__ blkhist, int2* __restrict__ part) {
    __shared__ int cur[NT];
    int b = blockIdx.x, t = threadIdx.x;
    for (int i = t; i < NT; i += 256) cur[i] = blkhist[b * NT + i];
    __syncthreads();
    int s = b * CHUNK, e = min(s + CHUNK, N_EDGES);
    for (int i = s + t; i < e; i += 256) {
        int r = row[i];
        int j = r >> 8;
        int p = atomicAdd(&cur[j], 1);
        part[p] = make_int2(((r & 255) << 24) | col[i], __float_as_int(val[i]));
    }
}

__global__ __launch_bounds__(256) void k_sort(const int2* __restrict__ part, const int* __restrict__ cnt,
                                              const int* __restrict__ base, int* __restrict__ row_ptr,
                                              int2* __restrict__ csr) {
    __shared__ int hist[256];
    __shared__ int cur[256];
    int b = blockIdx.x, t = threadIdx.x;
    int n = cnt[b];
    int bb = base[b];
    const int2* sl = part + bb;
    hist[t] = 0;
    __syncthreads();
    for (int i = t; i < n; i += 256) atomicAdd(&hist[((unsigned)sl[i].x) >> 24], 1);
    __syncthreads();
    int v = hist[t];
    for (int st = 1; st < 256; st <<= 1) {
        int u = (t >= st) ? hist[t - st] : 0;
        __syncthreads();
        hist[t] += u;
        __syncthreads();
    }
    cur[t] = hist[t] - v;
    int grow = b * 256 + t;
    if (grow < N_NODES) row_ptr[grow] = bb + cur[t];
    __syncthreads();
    for (int i = t; i < n; i += 256) {
        int2 e = sl[i];
        int rl = ((unsigned)e.x) >> 24;
        int p = atomicAdd(&cur[rl], 1);
        csr[bb + p] = make_int2(e.x & 0xFFFFFF, e.y);
    }
}

// ---------------- GEMM1: x[N,256] @ W1[256,32] -> support bf16 [N,32] ----------------
// Transposed x tile in LDS (k-major): compute-loop reads are broadcast/2-way (free).
__global__ __launch_bounds__(256) void k_gemm1(const float* __restrict__ x, const float* __restrict__ W,
                                               unsigned short* __restrict__ out) {
    __shared__ float xsT[64][66];                // [k][node], pad 66 keeps 8B align + low conflicts
    __shared__ __align__(16) float wc[64 * 32];  // [k][out] chunk
    int tid = threadIdx.x;
    int bn = blockIdx.x * 64;
    int tn = tid & 31;        // node pair: 2tn, 2tn+1
    int to = tid >> 5;        // out quad: 4to..4to+3
    float acc[2][4] = {};
    for (int kc = 0; kc < 4; ++kc) {
        int k0 = kc * 64;
        #pragma unroll
        for (int i = 0; i < 4; ++i) {
            int idx = i * 256 + tid;
            int n = idx >> 4;          // 0..63
            int k4 = (idx & 15) * 4;   // 0..60
            float4 v = make_float4(0.f, 0.f, 0.f, 0.f);
            if (bn + n < N_NODES)
                v = *reinterpret_cast<const float4*>(&x[(size_t)(bn + n) * 256 + k0 + k4]);
            xsT[k4 + 0][n] = v.x; xsT[k4 + 1][n] = v.y; xsT[k4 + 2][n] = v.z; xsT[k4 + 3][n] = v.w;
        }
        #pragma unroll
        for (int i = 0; i < 2; ++i) {
            int idx = i * 256 + tid;
            reinterpret_cast<float4*>(wc)[idx] =
                reinterpret_cast<const float4*>(W + (size_t)k0 * 32)[idx];
        }
        __syncthreads();
        #pragma unroll 8
        for (int k = 0; k < 64; ++k) {
            float2 a = *reinterpret_cast<const float2*>(&xsT[k][2 * tn]);
            float4 w = *reinterpret_cast<const float4*>(&wc[k * 32 + 4 * to]);
            acc[0][0] += a.x * w.x; acc[0][1] += a.x * w.y; acc[0][2] += a.x * w.z; acc[0][3] += a.x * w.w;
            acc[1][0] += a.y * w.x; acc[1][1] += a.y * w.y; acc[1][2] += a.y * w.z; acc[1][3] += a.y * w.w;
        }
        __syncthreads();
    }
    #pragma unroll
    for (int i = 0; i < 2; ++i) {
        int n = bn + 2 * tn + i;
        if (n < N_NODES) {
            ushort4 r;
            r.x = f2bf(acc[i][0]); r.y = f2bf(acc[i][1]);
            r.z = f2bf(acc[i][2]); r.w = f2bf(acc[i][3]);
            *reinterpret_cast<ushort4*>(&out[(size_t)n * 32 + 4 * to]) = r;
        }
    }
}

// ---------------- SpMM layer1: 4-chain unrolled gather ----------------
__global__ __launch_bounds__(256) void k_spmm1(const int* __restrict__ rp, const int2* __restrict__ csr,
                                               const unsigned short* __restrict__ sup,
                                               const float* __restrict__ bias,
                                               unsigned short* __restrict__ out) {
    int gid = blockIdx.x * 256 + threadIdx.x;
    int n = gid >> 5;
    int f = gid & 31;
    if (n >= N_NODES) return;
    int e0 = rp[n], e1 = rp[n + 1];
    float acc0 = 0.f, acc1 = 0.f, acc2 = 0.f, acc3 = 0.f;
    int e = e0;
    if ((e & 1) && e < e1) {                   // align to even index (16B)
        int2 a = csr[e];
        acc0 += __int_as_float(a.y) * b2f(sup[(size_t)a.x * 32 + f]);
        ++e;
    }
    for (; e + 3 < e1; e += 4) {
        int4 p = *reinterpret_cast<const int4*>(&csr[e]);
        int4 q = *reinterpret_cast<const int4*>(&csr[e + 2]);
        acc0 += __int_as_float(p.y) * b2f(sup[(size_t)p.x * 32 + f]);
        acc1 += __int_as_float(p.w) * b2f(sup[(size_t)p.z * 32 + f]);
        acc2 += __int_as_float(q.y) * b2f(sup[(size_t)q.x * 32 + f]);
        acc3 += __int_as_float(q.w) * b2f(sup[(size_t)q.z * 32 + f]);
    }
    for (; e < e1; ++e) {
        int2 a = csr[e];
        acc0 += __int_as_float(a.y) * b2f(sup[(size_t)a.x * 32 + f]);
    }
    float acc = fmaxf((acc0 + acc1) + (acc2 + acc3) + bias[f], 0.f);
    out[(size_t)n * 32 + f] = f2bf(acc);
}

// ---------------- layer2 fused: g2 = spmm(h1) ; h2 = relu(g2@W2+b2) bf16 ----------------
__global__ __launch_bounds__(256) void k_l2fused(const int* __restrict__ rp, const int2* __restrict__ csr,
                                                 const unsigned short* __restrict__ h1,
                                                 const float* __restrict__ W2, const float* __restrict__ b2,
                                                 unsigned short* __restrict__ h2) {
    __shared__ float w2s[32 * 48];
    __shared__ float b2s[48];
    __shared__ float g2s[8][33];
    int tid = threadIdx.x;
    for (int i = tid; i < 32 * 48; i += 256) w2s[i] = W2[i];
    if (tid < 48) b2s[tid] = b2[tid];
    int n0 = blockIdx.x * 8;
    int ln = tid >> 5, f = tid & 31;
    int n = n0 + ln;
    float acc0 = 0.f, acc1 = 0.f, acc2 = 0.f, acc3 = 0.f;
    {
        int e0 = rp[n], e1 = rp[n + 1];
        int e = e0;
        if ((e & 1) && e < e1) {
            int2 a = csr[e];
            acc0 += __int_as_float(a.y) * b2f(h1[(size_t)a.x * 32 + f]);
            ++e;
        }
        for (; e + 3 < e1; e += 4) {
            int4 p = *reinterpret_cast<const int4*>(&csr[e]);
            int4 q = *reinterpret_cast<const int4*>(&csr[e + 2]);
            acc0 += __int_as_float(p.y) * b2f(h1[(size_t)p.x * 32 + f]);
            acc1 += __int_as_float(p.w) * b2f(h1[(size_t)p.z * 32 + f]);
            acc2 += __int_as_float(q.y) * b2f(h1[(size_t)q.x * 32 + f]);
            acc3 += __int_as_float(q.w) * b2f(h1[(size_t)q.z * 32 + f]);
        }
        for (; e < e1; ++e) {
            int2 a = csr[e];
            acc0 += __int_as_float(a.y) * b2f(h1[(size_t)a.x * 32 + f]);
        }
    }
    g2s[ln][f] = (acc0 + acc1) + (acc2 + acc3);
    __syncthreads();
    for (int idx = tid; idx < 8 * 48; idx += 256) {
        int r = idx / 48;
        int m = idx - 48 * r;
        float a = b2s[m];
        const float* g = g2s[r];
        #pragma unroll
        for (int k = 0; k < 32; ++k) a += g[k] * w2s[k * 48 + m];
        h2[(size_t)(n0 + r) * 48 + m] = f2bf(fmaxf(a, 0.f));
    }
}

// ---------------- layer3 fused: g3 = spmm(h2); h3=relu(g3@W3+b3); pool partial ----------------
__global__ __launch_bounds__(256) void k_l3fused(const int* __restrict__ rp, const int2* __restrict__ csr,
                                                 const unsigned short* __restrict__ h2,
                                                 const float* __restrict__ W3, const float* __restrict__ b3,
                                                 float* __restrict__ poolpart) {
    __shared__ float w3s[48 * 64];
    __shared__ float b3s[64];
    __shared__ float g3s[5][49];
    __shared__ float red[256];
    int tid = threadIdx.x;
    for (int i = tid; i < 48 * 64; i += 256) w3s[i] = W3[i];
    if (tid < 64) b3s[tid] = b3[tid];
    int r5 = tid / 48;            // gather row 0..4 (tid<240)
    int f = tid - 48 * r5;
    int m = tid & 63;
    float poolacc = 0.f;
    for (int g = blockIdx.x; g < N_NODES / 5; g += L3_BLOCKS) {
        __syncthreads();          // protect g3s from previous dense reads
        if (tid < 240) {
            int n = g * 5 + r5;
            int e0 = rp[n], e1 = rp[n + 1];
            float acc0 = 0.f, acc1 = 0.f, acc2 = 0.f, acc3 = 0.f;
            int e = e0;
            if ((e & 1) && e < e1) {
                int2 a = csr[e];
                acc0 += __int_as_float(a.y) * b2f(h2[(size_t)a.x * 48 + f]);
                ++e;
            }
            for (; e + 3 < e1; e += 4) {
                int4 p = *reinterpret_cast<const int4*>(&csr[e]);
                int4 q = *reinterpret_cast<const int4*>(&csr[e + 2]);
                acc0 += __int_as_float(p.y) * b2f(h2[(size_t)p.x * 48 + f]);
                acc1 += __int_as_float(p.w) * b2f(h2[(size_t)p.z * 48 + f]);
                acc2 += __int_as_float(q.y) * b2f(h2[(size_t)q.x * 48 + f]);
                acc3 += __int_as_float(q.w) * b2f(h2[(size_t)q.z * 48 + f]);
            }
            for (; e < e1; ++e) {
                int2 a = csr[e];
                acc0 += __int_as_float(a.y) * b2f(h2[(size_t)a.x * 48 + f]);
            }
            g3s[r5][f] = (acc0 + acc1) + (acc2 + acc3);
        }
        __syncthreads();
        {
            int r = tid >> 6;
            float a = b3s[m];
            const float* gg = g3s[r];
            #pragma unroll
            for (int k = 0; k < 48; ++k) a += gg[k] * w3s[k * 64 + m];
            poolacc += fmaxf(a, 0.f);
        }
        if (tid < 64) {
            float a = b3s[m];
            const float* gg = g3s[4];
            #pragma unroll
            for (int k = 0; k < 48; ++k) a += gg[k] * w3s[k * 64 + m];
            poolacc += fmaxf(a, 0.f);
        }
    }
    __syncthreads();
    red[tid] = poolacc;
    __syncthreads();
    if (tid < 64) {
        float s = red[tid] + red[tid + 64] + red[tid + 128] + red[tid + 192];
        poolpart[(size_t)blockIdx.x * 64 + tid] = s;
    }
}

// ---------------- pool reduce: poolpart[2000][64] -> pool[64] (64 blocks) ----------------
__global__ __launch_bounds__(256) void k_preduce(const float* __restrict__ poolpart,
                                                 float* __restrict__ pool) {
    __shared__ float red[256];
    int b = blockIdx.x, t = threadIdx.x;
    float s = 0.f;
    for (int j = t; j < L3_BLOCKS; j += 256) s += poolpart[(size_t)j * 64 + b];
    red[t] = s;
    __syncthreads();
    for (int st = 128; st > 0; st >>= 1) {
        if (t < st) red[t] += red[t + st];
        __syncthreads();
    }
    if (t == 0) pool[b] = red[0];
}

// ---------------- head: mean -> FC1+relu -> FC2 -> softmax (tiny) ----------------
__global__ __launch_bounds__(64) void k_head(const float* __restrict__ pool,
                                             const float* __restrict__ fc1W, const float* __restrict__ fc1b,
                                             const float* __restrict__ fc2W, const float* __restrict__ fc2b,
                                             float* __restrict__ out) {
    __shared__ float pl[64];
    __shared__ float z[32];
    __shared__ float lg[2];
    int t = threadIdx.x;
    pl[t] = pool[t] * (1.0f / (float)N_NODES);
    __syncthreads();
    if (t < 32) {
        float a = fc1b[t];
        #pragma unroll
        for (int o = 0; o < 64; ++o) a += pl[o] * fc1W[o * 32 + t];
        z[t] = fmaxf(a, 0.f);
    }
    __syncthreads();
    if (t < 2) {
        float l = fc2b[t];
        #pragma unroll
        for (int j = 0; j < 32; ++j) l += z[j] * fc2W[j * 2 + t];
        lg[t] = l;
    }
    __syncthreads();
    if (t == 0) {
        float mx = fmaxf(lg[0], lg[1]);
        float e0 = __expf(lg[0] - mx), e1 = __expf(lg[1] - mx);
        float ss = e0 + e1;
        out[0] = e0 / ss;
        out[1] = e1 / ss;
    }
}

// ---------------- launch ----------------

extern "C" void kernel_launch(void* const* d_in, const int* in_sizes, int n_in,
                              void* d_out, int out_size, void* d_ws, size_t ws_size,
                              hipStream_t stream) {
    const float* x    = (const float*)d_in[0];
    const int*   row  = (const int*)d_in[1];
    const int*   col  = (const int*)d_in[2];
    const float* val  = (const float*)d_in[3];
    const float* W1   = (const float*)d_in[4];
    const float* b1   = (const float*)d_in[5];
    const float* W2   = (const float*)d_in[6];
    const float* b2   = (const float*)d_in[7];
    const float* W3   = (const float*)d_in[8];
    const float* b3   = (const float*)d_in[9];
    const float* fc1W = (const float*)d_in[10];
    const float* fc1b = (const float*)d_in[11];
    const float* fc2W = (const float*)d_in[12];
    const float* fc2b = (const float*)d_in[13];
    float* out = (float*)d_out;

    char* wsb = (char*)d_ws;
    size_t off = 0;
    auto alloc = [&](size_t bytes) {
        void* p = wsb + off;
        off += (bytes + 255) / 256 * 256;
        return p;
    };
    int*   blkhist  = (int*)alloc((size_t)NT * NB1 * 4);
    int*   base     = (int*)alloc((size_t)NT * 4);
    int*   cnt      = (int*)alloc((size_t)NT * 4);
    int*   row_ptr  = (int*)alloc((size_t)(N_NODES + 1) * 4);
    int2*  part     = (int2*)alloc((size_t)N_EDGES * 8);
    int2*  csr      = (int2*)alloc((size_t)N_EDGES * 8);
    unsigned short* sup = (unsigned short*)alloc((size_t)N_NODES * 32 * 2);
    unsigned short* h1  = (unsigned short*)alloc((size_t)N_NODES * 32 * 2);
    unsigned short* h2  = (unsigned short*)alloc((size_t)N_NODES * 48 * 2);
    float* poolpart = (float*)alloc((size_t)L3_BLOCKS * 64 * 4);
    float* pool     = (float*)alloc(64 * 4);

    // CSR build (no global atomics)
    k_phist<<<NB1, 256, 0, stream>>>(row, blkhist);
    k_pscan<<<1, 512, 0, stream>>>(blkhist, base, cnt, row_ptr);
    k_pscatter<<<NB1, 256, 0, stream>>>(row, col, val, blkhist, part);
    k_sort<<<NT, 256, 0, stream>>>(part, cnt, base, row_ptr, csr);

    // layer 1
    k_gemm1<<<(N_NODES + 63) / 64, 256, 0, stream>>>(x, W1, sup);
    k_spmm1<<<(N_NODES * 32) / 256, 256, 0, stream>>>(row_ptr, csr, sup, b1, h1);
    // layer 2 fused
    k_l2fused<<<N_NODES / 8, 256, 0, stream>>>(row_ptr, csr, h1, W2, b2, h2);
    // layer 3 fused + pool partials
    k_l3fused<<<L3_BLOCKS, 256, 0, stream>>>(row_ptr, csr, h2, W3, b3, poolpart);
    // pool reduce + head
    k_preduce<<<64, 256, 0, stream>>>(poolpart, pool);
    k_head<<<1, 64, 0, stream>>>(pool, fc1W, fc1b, fc2W, fc2b, out);
}

// Round 7
// 264.168 us; speedup vs baseline: 1.8843x; 1.1647x over previous
//
#include <hip/hip_runtime.h>
#include <hip/hip_bf16.h>

#define N_NODES 100000
#define N_EDGES 1600000

#define NT 391                               // row buckets of 256 rows
#define NB1 128                              // partition blocks
#define CHUNK ((N_EDGES + NB1 - 1) / NB1)    // 12500 edges per block
#define ROWS3 20                             // rows per l3fused iteration
#define ITER3 (N_NODES / ROWS3)              // 5000
#define GRID3 2500                           // l3fused blocks (2 iters each)

// ---------------- fp8 e4m3 helpers (HW converts, gfx950 OCP) ----------------
__device__ __forceinline__ unsigned char f2q(float f) {
    return (unsigned char)(__builtin_amdgcn_cvt_pk_fp8_f32(f, f, 0, false) & 0xFF);
}
__device__ __forceinline__ unsigned pack4_fp8(float a0, float a1, float a2, float a3) {
    int r = __builtin_amdgcn_cvt_pk_fp8_f32(a0, a1, 0, false);
    r = __builtin_amdgcn_cvt_pk_fp8_f32(a2, a3, r, true);
    return (unsigned)r;
}

// ---------------- CSR build: contention-free two-pass bucket partition ----------------

__global__ __launch_bounds__(256) void k_phist(const int* __restrict__ row, int* __restrict__ blkhist) {
    __shared__ int h[NT];
    int b = blockIdx.x, t = threadIdx.x;
    for (int i = t; i < NT; i += 256) h[i] = 0;
    __syncthreads();
    int s = b * CHUNK, e = min(s + CHUNK, N_EDGES);
    for (int i = s + t; i < e; i += 256) atomicAdd(&h[row[i] >> 8], 1);
    __syncthreads();
    for (int i = t; i < NT; i += 256) blkhist[b * NT + i] = h[i];   // b-major
}

__global__ __launch_bounds__(512) void k_pscan(int* __restrict__ blkhist, int* __restrict__ base,
                                               int* __restrict__ cnt, int* __restrict__ row_ptr) {
    __shared__ int s[512];
    int j = threadIdx.x;
    int tot = 0;
    if (j < NT) {
        for (int b = 0; b < NB1; ++b) {                  // coalesced across j
            int v = blkhist[b * NT + j];
            blkhist[b * NT + j] = tot;
            tot += v;
        }
    }
    s[j] = (j < NT) ? tot : 0;
    __syncthreads();
    for (int st = 1; st < 512; st <<= 1) {
        int u = (j >= st) ? s[j - st] : 0;
        __syncthreads();
        s[j] += u;
        __syncthreads();
    }
    if (j < NT) {
        int bs = s[j] - tot;                             // exclusive bucket base
        base[j] = bs;
        cnt[j] = tot;
        for (int b = 0; b < NB1; ++b) blkhist[b * NT + j] += bs;
    }
    if (j == 0) row_ptr[N_NODES] = N_EDGES;
}

__global__ __launch_bounds__(256) void k_pscatter(const int* __restrict__ row, const int* __restrict__ col,
                                                  const float* __restrict__ val,
                                                  const int* __restrict__ blkhist, int2* __restrict__ part) {
    __shared__ int cur[NT];
    int b = blockIdx.x, t = threadIdx.x;
    for (int i = t; i < NT; i += 256) cur[i] = blkhist[b * NT + i];
    __syncthreads();
    int s = b * CHUNK, e = min(s + CHUNK, N_EDGES);
    for (int i = s + t; i < e; i += 256) {
        int r = row[i];
        int j = r >> 8;
        int p = atomicAdd(&cur[j], 1);
        part[p] = make_int2(((r & 255) << 24) | col[i], __float_as_int(val[i]));
    }
}

// Pass 4: per-bucket LDS counting sort -> final packed u32 CSR (col<<15 | q15(val)) + row_ptr.
__global__ __launch_bounds__(256) void k_sort(const int2* __restrict__ part, const int* __restrict__ cnt,
                                              const int* __restrict__ base, int* __restrict__ row_ptr,
                                              unsigned* __restrict__ csr) {
    __shared__ int hist[256];
    __shared__ int cur[256];
    int b = blockIdx.x, t = threadIdx.x;
    int n = cnt[b];
    int bb = base[b];
    const int2* sl = part + bb;
    hist[t] = 0;
    __syncthreads();
    for (int i = t; i < n; i += 256) atomicAdd(&hist[((unsigned)sl[i].x) >> 24], 1);
    __syncthreads();
    int v = hist[t];
    for (int st = 1; st < 256; st <<= 1) {
        int u = (t >= st) ? hist[t - st] : 0;
        __syncthreads();
        hist[t] += u;
        __syncthreads();
    }
    cur[t] = hist[t] - v;
    int grow = b * 256 + t;
    if (grow < N_NODES) row_ptr[grow] = bb + cur[t];
    __syncthreads();
    for (int i = t; i < n; i += 256) {
        int2 e = sl[i];
        int rl = ((unsigned)e.x) >> 24;
        int p = atomicAdd(&cur[rl], 1);
        unsigned c = (unsigned)(e.x & 0xFFFFFF);
        float vf = __int_as_float(e.y);
        int q = __float2int_rn(vf * 32768.0f);
        if (q > 32767) q = 32767;
        csr[bb + p] = (c << 15) | (unsigned)q;
    }
}

// ---------------- GEMM1: x[N,256] @ W1[256,32] -> support fp8 [N,32] ----------------
__global__ __launch_bounds__(256) void k_gemm1(const float* __restrict__ x, const float* __restrict__ W,
                                               unsigned char* __restrict__ out) {
    __shared__ float xsT[64][66];
    __shared__ __align__(16) float wc[64 * 32];
    int tid = threadIdx.x;
    int bn = blockIdx.x * 64;
    int tn = tid & 31;        // node pair: 2tn, 2tn+1
    int to = tid >> 5;        // out quad: 4to..4to+3
    float acc[2][4] = {};
    for (int kc = 0; kc < 4; ++kc) {
        int k0 = kc * 64;
        #pragma unroll
        for (int i = 0; i < 4; ++i) {
            int idx = i * 256 + tid;
            int n = idx >> 4;
            int k4 = (idx & 15) * 4;
            float4 v = make_float4(0.f, 0.f, 0.f, 0.f);
            if (bn + n < N_NODES)
                v = *reinterpret_cast<const float4*>(&x[(size_t)(bn + n) * 256 + k0 + k4]);
            xsT[k4 + 0][n] = v.x; xsT[k4 + 1][n] = v.y; xsT[k4 + 2][n] = v.z; xsT[k4 + 3][n] = v.w;
        }
        #pragma unroll
        for (int i = 0; i < 2; ++i) {
            int idx = i * 256 + tid;
            reinterpret_cast<float4*>(wc)[idx] =
                reinterpret_cast<const float4*>(W + (size_t)k0 * 32)[idx];
        }
        __syncthreads();
        #pragma unroll 8
        for (int k = 0; k < 64; ++k) {
            float2 a = *reinterpret_cast<const float2*>(&xsT[k][2 * tn]);
            float4 w = *reinterpret_cast<const float4*>(&wc[k * 32 + 4 * to]);
            acc[0][0] += a.x * w.x; acc[0][1] += a.x * w.y; acc[0][2] += a.x * w.z; acc[0][3] += a.x * w.w;
            acc[1][0] += a.y * w.x; acc[1][1] += a.y * w.y; acc[1][2] += a.y * w.z; acc[1][3] += a.y * w.w;
        }
        __syncthreads();
    }
    #pragma unroll
    for (int i = 0; i < 2; ++i) {
        int n = bn + 2 * tn + i;
        if (n < N_NODES) {
            unsigned r = pack4_fp8(acc[i][0], acc[i][1], acc[i][2], acc[i][3]);
            *reinterpret_cast<unsigned*>(&out[(size_t)n * 32 + 4 * to]) = r;
        }
    }
}

// ---------------- SpMM layer1: 8 lanes x uchar4 per row, F=32 ----------------
__global__ __launch_bounds__(256) void k_spmm1(const int* __restrict__ rp, const unsigned* __restrict__ csr,
                                               const unsigned char* __restrict__ sup,
                                               const float* __restrict__ bias,
                                               unsigned char* __restrict__ out) {
    int gid = blockIdx.x * 256 + threadIdx.x;
    int n = gid >> 3;
    int f4 = (gid & 7) * 4;
    int e0 = rp[n], e1 = rp[n + 1];
    float a0 = 0.f, a1 = 0.f, a2 = 0.f, a3 = 0.f;
    int e = e0;
    for (; (e & 3) && e < e1; ++e) {
        unsigned ent = csr[e];
        float v = (float)(ent & 0x7FFF);
        unsigned u = *reinterpret_cast<const unsigned*>(&sup[(size_t)(ent >> 15) * 32 + f4]);
        a0 += v * __builtin_amdgcn_cvt_f32_fp8(u, 0);
        a1 += v * __builtin_amdgcn_cvt_f32_fp8(u, 1);
        a2 += v * __builtin_amdgcn_cvt_f32_fp8(u, 2);
        a3 += v * __builtin_amdgcn_cvt_f32_fp8(u, 3);
    }
    for (; e + 3 < e1; e += 4) {
        uint4 p = *reinterpret_cast<const uint4*>(&csr[e]);
        unsigned u0 = *reinterpret_cast<const unsigned*>(&sup[(size_t)(p.x >> 15) * 32 + f4]);
        unsigned u1 = *reinterpret_cast<const unsigned*>(&sup[(size_t)(p.y >> 15) * 32 + f4]);
        unsigned u2 = *reinterpret_cast<const unsigned*>(&sup[(size_t)(p.z >> 15) * 32 + f4]);
        unsigned u3 = *reinterpret_cast<const unsigned*>(&sup[(size_t)(p.w >> 15) * 32 + f4]);
        float v0 = (float)(p.x & 0x7FFF), v1 = (float)(p.y & 0x7FFF);
        float v2 = (float)(p.z & 0x7FFF), v3 = (float)(p.w & 0x7FFF);
        a0 += v0 * __builtin_amdgcn_cvt_f32_fp8(u0, 0) + v1 * __builtin_amdgcn_cvt_f32_fp8(u1, 0)
            + v2 * __builtin_amdgcn_cvt_f32_fp8(u2, 0) + v3 * __builtin_amdgcn_cvt_f32_fp8(u3, 0);
        a1 += v0 * __builtin_amdgcn_cvt_f32_fp8(u0, 1) + v1 * __builtin_amdgcn_cvt_f32_fp8(u1, 1)
            + v2 * __builtin_amdgcn_cvt_f32_fp8(u2, 1) + v3 * __builtin_amdgcn_cvt_f32_fp8(u3, 1);
        a2 += v0 * __builtin_amdgcn_cvt_f32_fp8(u0, 2) + v1 * __builtin_amdgcn_cvt_f32_fp8(u1, 2)
            + v2 * __builtin_amdgcn_cvt_f32_fp8(u2, 2) + v3 * __builtin_amdgcn_cvt_f32_fp8(u3, 2);
        a3 += v0 * __builtin_amdgcn_cvt_f32_fp8(u0, 3) + v1 * __builtin_amdgcn_cvt_f32_fp8(u1, 3)
            + v2 * __builtin_amdgcn_cvt_f32_fp8(u2, 3) + v3 * __builtin_amdgcn_cvt_f32_fp8(u3, 3);
    }
    for (; e < e1; ++e) {
        unsigned ent = csr[e];
        float v = (float)(ent & 0x7FFF);
        unsigned u = *reinterpret_cast<const unsigned*>(&sup[(size_t)(ent >> 15) * 32 + f4]);
        a0 += v * __builtin_amdgcn_cvt_f32_fp8(u, 0);
        a1 += v * __builtin_amdgcn_cvt_f32_fp8(u, 1);
        a2 += v * __builtin_amdgcn_cvt_f32_fp8(u, 2);
        a3 += v * __builtin_amdgcn_cvt_f32_fp8(u, 3);
    }
    const float sc = 1.0f / 32768.0f;
    unsigned r = pack4_fp8(fmaxf(a0 * sc + bias[f4 + 0], 0.f), fmaxf(a1 * sc + bias[f4 + 1], 0.f),
                           fmaxf(a2 * sc + bias[f4 + 2], 0.f), fmaxf(a3 * sc + bias[f4 + 3], 0.f));
    *reinterpret_cast<unsigned*>(&out[(size_t)n * 32 + f4]) = r;
}

// ---------------- layer2 fused: g2 = spmm(h1); h2 = relu(g2@W2+b2) fp8. 32 rows/block ----------------
__global__ __launch_bounds__(256) void k_l2fused(const int* __restrict__ rp, const unsigned* __restrict__ csr,
                                                 const unsigned char* __restrict__ h1,
                                                 const float* __restrict__ W2, const float* __restrict__ b2,
                                                 unsigned char* __restrict__ h2) {
    __shared__ float w2s[32 * 48];
    __shared__ float b2s[48];
    __shared__ float g2s[32][33];
    int tid = threadIdx.x;
    for (int i = tid; i < 32 * 48; i += 256) w2s[i] = W2[i];
    if (tid < 48) b2s[tid] = b2[tid];
    int n0 = blockIdx.x * 32;
    int grp = tid >> 3;
    int f4 = (tid & 7) * 4;
    int n = n0 + grp;
    float a0 = 0.f, a1 = 0.f, a2 = 0.f, a3 = 0.f;
    {
        int e0 = rp[n], e1 = rp[n + 1];
        int e = e0;
        for (; (e & 3) && e < e1; ++e) {
            unsigned ent = csr[e];
            float v = (float)(ent & 0x7FFF);
            unsigned u = *reinterpret_cast<const unsigned*>(&h1[(size_t)(ent >> 15) * 32 + f4]);
            a0 += v * __builtin_amdgcn_cvt_f32_fp8(u, 0);
            a1 += v * __builtin_amdgcn_cvt_f32_fp8(u, 1);
            a2 += v * __builtin_amdgcn_cvt_f32_fp8(u, 2);
            a3 += v * __builtin_amdgcn_cvt_f32_fp8(u, 3);
        }
        for (; e + 3 < e1; e += 4) {
            uint4 p = *reinterpret_cast<const uint4*>(&csr[e]);
            unsigned u0 = *reinterpret_cast<const unsigned*>(&h1[(size_t)(p.x >> 15) * 32 + f4]);
            unsigned u1 = *reinterpret_cast<const unsigned*>(&h1[(size_t)(p.y >> 15) * 32 + f4]);
            unsigned u2 = *reinterpret_cast<const unsigned*>(&h1[(size_t)(p.z >> 15) * 32 + f4]);
            unsigned u3 = *reinterpret_cast<const unsigned*>(&h1[(size_t)(p.w >> 15) * 32 + f4]);
            float v0 = (float)(p.x & 0x7FFF), v1 = (float)(p.y & 0x7FFF);
            float v2 = (float)(p.z & 0x7FFF), v3 = (float)(p.w & 0x7FFF);
            a0 += v0 * __builtin_amdgcn_cvt_f32_fp8(u0, 0) + v1 * __builtin_amdgcn_cvt_f32_fp8(u1, 0)
                + v2 * __builtin_amdgcn_cvt_f32_fp8(u2, 0) + v3 * __builtin_amdgcn_cvt_f32_fp8(u3, 0);
            a1 += v0 * __builtin_amdgcn_cvt_f32_fp8(u0, 1) + v1 * __builtin_amdgcn_cvt_f32_fp8(u1, 1)
                + v2 * __builtin_amdgcn_cvt_f32_fp8(u2, 1) + v3 * __builtin_amdgcn_cvt_f32_fp8(u3, 1);
            a2 += v0 * __builtin_amdgcn_cvt_f32_fp8(u0, 2) + v1 * __builtin_amdgcn_cvt_f32_fp8(u1, 2)
                + v2 * __builtin_amdgcn_cvt_f32_fp8(u2, 2) + v3 * __builtin_amdgcn_cvt_f32_fp8(u3, 2);
            a3 += v0 * __builtin_amdgcn_cvt_f32_fp8(u0, 3) + v1 * __builtin_amdgcn_cvt_f32_fp8(u1, 3)
                + v2 * __builtin_amdgcn_cvt_f32_fp8(u2, 3) + v3 * __builtin_amdgcn_cvt_f32_fp8(u3, 3);
        }
        for (; e < e1; ++e) {
            unsigned ent = csr[e];
            float v = (float)(ent & 0x7FFF);
            unsigned u = *reinterpret_cast<const unsigned*>(&h1[(size_t)(ent >> 15) * 32 + f4]);
            a0 += v * __builtin_amdgcn_cvt_f32_fp8(u, 0);
            a1 += v * __builtin_amdgcn_cvt_f32_fp8(u, 1);
            a2 += v * __builtin_amdgcn_cvt_f32_fp8(u, 2);
            a3 += v * __builtin_amdgcn_cvt_f32_fp8(u, 3);
        }
    }
    const float sc = 1.0f / 32768.0f;
    g2s[grp][f4 + 0] = a0 * sc;
    g2s[grp][f4 + 1] = a1 * sc;
    g2s[grp][f4 + 2] = a2 * sc;
    g2s[grp][f4 + 3] = a3 * sc;
    __syncthreads();
    for (int idx = tid; idx < 32 * 48; idx += 256) {
        int r = idx / 48;
        int m = idx - 48 * r;
        float a = b2s[m];
        const float* g = g2s[r];
        #pragma unroll
        for (int k = 0; k < 32; ++k) a += g[k] * w2s[k * 48 + m];
        h2[(size_t)(n0 + r) * 48 + m] = f2q(fmaxf(a, 0.f));
    }
}

// ---------------- layer3 fused: g3 = spmm(h2); relu(g3@W3+b3); pool partial. 20 rows/iter ----------------
__global__ __launch_bounds__(256) void k_l3fused(const int* __restrict__ rp, const unsigned* __restrict__ csr,
                                                 const unsigned char* __restrict__ h2,
                                                 const float* __restrict__ W3, const float* __restrict__ b3,
                                                 float* __restrict__ poolpart) {
    __shared__ float w3s[48 * 64];
    __shared__ float b3s[64];
    __shared__ float g3s[ROWS3][49];
    __shared__ float red[256];
    int tid = threadIdx.x;
    for (int i = tid; i < 48 * 64; i += 256) w3s[i] = W3[i];
    if (tid < 64) b3s[tid] = b3[tid];
    int grp = tid / 12;                       // 0..19 for tid<240
    int f4 = (tid - grp * 12) * 4;            // 0..44
    int m = tid & 63;
    const float sc = 1.0f / 32768.0f;
    float poolacc = 0.f;
    for (int g = blockIdx.x; g < ITER3; g += GRID3) {
        __syncthreads();          // protect g3s from previous dense reads
        if (tid < 240) {
            int n = g * ROWS3 + grp;
            int e0 = rp[n], e1 = rp[n + 1];
            float a0 = 0.f, a1 = 0.f, a2 = 0.f, a3 = 0.f;
            int e = e0;
            for (; (e & 3) && e < e1; ++e) {
                unsigned ent = csr[e];
                float v = (float)(ent & 0x7FFF);
                unsigned u = *reinterpret_cast<const unsigned*>(&h2[(size_t)(ent >> 15) * 48 + f4]);
                a0 += v * __builtin_amdgcn_cvt_f32_fp8(u, 0);
                a1 += v * __builtin_amdgcn_cvt_f32_fp8(u, 1);
                a2 += v * __builtin_amdgcn_cvt_f32_fp8(u, 2);
                a3 += v * __builtin_amdgcn_cvt_f32_fp8(u, 3);
            }
            for (; e + 3 < e1; e += 4) {
                uint4 p = *reinterpret_cast<const uint4*>(&csr[e]);
                unsigned u0 = *reinterpret_cast<const unsigned*>(&h2[(size_t)(p.x >> 15) * 48 + f4]);
                unsigned u1 = *reinterpret_cast<const unsigned*>(&h2[(size_t)(p.y >> 15) * 48 + f4]);
                unsigned u2 = *reinterpret_cast<const unsigned*>(&h2[(size_t)(p.z >> 15) * 48 + f4]);
                unsigned u3 = *reinterpret_cast<const unsigned*>(&h2[(size_t)(p.w >> 15) * 48 + f4]);
                float v0 = (float)(p.x & 0x7FFF), v1 = (float)(p.y & 0x7FFF);
                float v2 = (float)(p.z & 0x7FFF), v3 = (float)(p.w & 0x7FFF);
                a0 += v0 * __builtin_amdgcn_cvt_f32_fp8(u0, 0) + v1 * __builtin_amdgcn_cvt_f32_fp8(u1, 0)
                    + v2 * __builtin_amdgcn_cvt_f32_fp8(u2, 0) + v3 * __builtin_amdgcn_cvt_f32_fp8(u3, 0);
                a1 += v0 * __builtin_amdgcn_cvt_f32_fp8(u0, 1) + v1 * __builtin_amdgcn_cvt_f32_fp8(u1, 1)
                    + v2 * __builtin_amdgcn_cvt_f32_fp8(u2, 1) + v3 * __builtin_amdgcn_cvt_f32_fp8(u3, 1);
                a2 += v0 * __builtin_amdgcn_cvt_f32_fp8(u0, 2) + v1 * __builtin_amdgcn_cvt_f32_fp8(u1, 2)
                    + v2 * __builtin_amdgcn_cvt_f32_fp8(u2, 2) + v3 * __builtin_amdgcn_cvt_f32_fp8(u3, 2);
                a3 += v0 * __builtin_amdgcn_cvt_f32_fp8(u0, 3) + v1 * __builtin_amdgcn_cvt_f32_fp8(u1, 3)
                    + v2 * __builtin_amdgcn_cvt_f32_fp8(u2, 3) + v3 * __builtin_amdgcn_cvt_f32_fp8(u3, 3);
            }
            for (; e < e1; ++e) {
                unsigned ent = csr[e];
                float v = (float)(ent & 0x7FFF);
                unsigned u = *reinterpret_cast<const unsigned*>(&h2[(size_t)(ent >> 15) * 48 + f4]);
                a0 += v * __builtin_amdgcn_cvt_f32_fp8(u, 0);
                a1 += v * __builtin_amdgcn_cvt_f32_fp8(u, 1);
                a2 += v * __builtin_amdgcn_cvt_f32_fp8(u, 2);
                a3 += v * __builtin_amdgcn_cvt_f32_fp8(u, 3);
            }
            g3s[grp][f4 + 0] = a0 * sc;
            g3s[grp][f4 + 1] = a1 * sc;
            g3s[grp][f4 + 2] = a2 * sc;
            g3s[grp][f4 + 3] = a3 * sc;
        }
        __syncthreads();
        #pragma unroll
        for (int p = 0; p < 5; ++p) {
            int r = 4 * p + (tid >> 6);
            float a = b3s[m];
            const float* gg = g3s[r];
            #pragma unroll
            for (int k = 0; k < 48; ++k) a += gg[k] * w3s[k * 64 + m];
            poolacc += fmaxf(a, 0.f);
        }
    }
    __syncthreads();
    red[tid] = poolacc;
    __syncthreads();
    if (tid < 64) {
        float s = red[tid] + red[tid + 64] + red[tid + 128] + red[tid + 192];
        poolpart[(size_t)blockIdx.x * 64 + tid] = s;
    }
}

// ---------------- pool reduce: poolpart[GRID3][64] -> pool[64] (64 blocks) ----------------
__global__ __launch_bounds__(256) void k_preduce(const float* __restrict__ poolpart,
                                                 float* __restrict__ pool) {
    __shared__ float red[256];
    int b = blockIdx.x, t = threadIdx.x;
    float s = 0.f;
    for (int j = t; j < GRID3; j += 256) s += poolpart[(size_t)j * 64 + b];
    red[t] = s;
    __syncthreads();
    for (int st = 128; st > 0; st >>= 1) {
        if (t < st) red[t] += red[t + st];
        __syncthreads();
    }
    if (t == 0) pool[b] = red[0];
}

// ---------------- head: mean -> FC1+relu -> FC2 -> softmax (tiny) ----------------
__global__ __launch_bounds__(64) void k_head(const float* __restrict__ pool,
                                             const float* __restrict__ fc1W, const float* __restrict__ fc1b,
                                             const float* __restrict__ fc2W, const float* __restrict__ fc2b,
                                             float* __restrict__ out) {
    __shared__ float pl[64];
    __shared__ float z[32];
    __shared__ float lg[2];
    int t = threadIdx.x;
    pl[t] = pool[t] * (1.0f / (float)N_NODES);
    __syncthreads();
    if (t < 32) {
        float a = fc1b[t];
        #pragma unroll
        for (int o = 0; o < 64; ++o) a += pl[o] * fc1W[o * 32 + t];
        z[t] = fmaxf(a, 0.f);
    }
    __syncthreads();
    if (t < 2) {
        float l = fc2b[t];
        #pragma unroll
        for (int j = 0; j < 32; ++j) l += z[j] * fc2W[j * 2 + t];
        lg[t] = l;
    }
    __syncthreads();
    if (t == 0) {
        float mx = fmaxf(lg[0], lg[1]);
        float e0 = __expf(lg[0] - mx), e1 = __expf(lg[1] - mx);
        float ss = e0 + e1;
        out[0] = e0 / ss;
        out[1] = e1 / ss;
    }
}

// ---------------- launch ----------------

extern "C" void kernel_launch(void* const* d_in, const int* in_sizes, int n_in,
                              void* d_out, int out_size, void* d_ws, size_t ws_size,
                              hipStream_t stream) {
    const float* x    = (const float*)d_in[0];
    const int*   row  = (const int*)d_in[1];
    const int*   col  = (const int*)d_in[2];
    const float* val  = (const float*)d_in[3];
    const float* W1   = (const float*)d_in[4];
    const float* b1   = (const float*)d_in[5];
    const float* W2   = (const float*)d_in[6];
    const float* b2   = (const float*)d_in[7];
    const float* W3   = (const float*)d_in[8];
    const float* b3   = (const float*)d_in[9];
    const float* fc1W = (const float*)d_in[10];
    const float* fc1b = (const float*)d_in[11];
    const float* fc2W = (const float*)d_in[12];
    const float* fc2b = (const float*)d_in[13];
    float* out = (float*)d_out;

    char* wsb = (char*)d_ws;
    size_t off = 0;
    auto alloc = [&](size_t bytes) {
        void* p = wsb + off;
        off += (bytes + 255) / 256 * 256;
        return p;
    };
    int*      blkhist  = (int*)alloc((size_t)NT * NB1 * 4);
    int*      base     = (int*)alloc((size_t)NT * 4);
    int*      cnt      = (int*)alloc((size_t)NT * 4);
    int*      row_ptr  = (int*)alloc((size_t)(N_NODES + 1) * 4);
    int2*     part     = (int2*)alloc((size_t)N_EDGES * 8);
    unsigned* csr      = (unsigned*)alloc((size_t)N_EDGES * 4);
    unsigned char* sup = (unsigned char*)alloc((size_t)N_NODES * 32);
    unsigned char* h1  = (unsigned char*)alloc((size_t)N_NODES * 32);
    unsigned char* h2  = (unsigned char*)alloc((size_t)N_NODES * 48);
    float* poolpart    = (float*)alloc((size_t)GRID3 * 64 * 4);
    float* pool        = (float*)alloc(64 * 4);

    // CSR build (no global atomics)
    k_phist<<<NB1, 256, 0, stream>>>(row, blkhist);
    k_pscan<<<1, 512, 0, stream>>>(blkhist, base, cnt, row_ptr);
    k_pscatter<<<NB1, 256, 0, stream>>>(row, col, val, blkhist, part);
    k_sort<<<NT, 256, 0, stream>>>(part, cnt, base, row_ptr, csr);

    // layer 1
    k_gemm1<<<(N_NODES + 63) / 64, 256, 0, stream>>>(x, W1, sup);
    k_spmm1<<<(N_NODES * 8) / 256, 256, 0, stream>>>(row_ptr, csr, sup, b1, h1);
    // layer 2 fused (32 rows/block)
    k_l2fused<<<N_NODES / 32, 256, 0, stream>>>(row_ptr, csr, h1, W2, b2, h2);
    // layer 3 fused + pool partials (20 rows/iter)
    k_l3fused<<<GRID3, 256, 0, stream>>>(row_ptr, csr, h2, W3, b3, poolpart);
    // pool reduce + head
    k_preduce<<<64, 256, 0, stream>>>(poolpart, pool);
    k_head<<<1, 64, 0, stream>>>(pool, fc1W, fc1b, fc2W, fc2b, out);
}

// Round 8
// 233.527 us; speedup vs baseline: 2.1315x; 1.1312x over previous
//
#include <hip/hip_runtime.h>
#include <hip/hip_bf16.h>

#define N_NODES 100000
#define N_EDGES 1600000

#define NT 391                               // row buckets of 256 rows
#define NB1 128                              // partition blocks
#define CHUNK ((N_EDGES + NB1 - 1) / NB1)    // 12500 edges per block
#define ROWS3 40                             // rows per l3fused block
#define GRID3 (N_NODES / ROWS3)              // 2500

// ---------------- fp8 e4m3 helpers (HW converts, gfx950 OCP) ----------------
__device__ __forceinline__ unsigned char f2q(float f) {
    return (unsigned char)(__builtin_amdgcn_cvt_pk_fp8_f32(f, f, 0, false) & 0xFF);
}
__device__ __forceinline__ unsigned pack4_fp8(float a0, float a1, float a2, float a3) {
    int r = __builtin_amdgcn_cvt_pk_fp8_f32(a0, a1, 0, false);
    r = __builtin_amdgcn_cvt_pk_fp8_f32(a2, a3, r, true);
    return (unsigned)r;
}
#define CVT(u, s) __builtin_amdgcn_cvt_f32_fp8((u), (s))

// ---------------- CSR build: contention-free two-pass bucket partition ----------------

__global__ __launch_bounds__(256) void k_phist(const int* __restrict__ row, int* __restrict__ blkhist) {
    __shared__ int h[NT];
    int b = blockIdx.x, t = threadIdx.x;
    for (int i = t; i < NT; i += 256) h[i] = 0;
    __syncthreads();
    int s = b * CHUNK, e = min(s + CHUNK, N_EDGES);
    for (int i = s + t; i < e; i += 256) atomicAdd(&h[row[i] >> 8], 1);
    __syncthreads();
    for (int i = t; i < NT; i += 256) blkhist[b * NT + i] = h[i];   // b-major
}

__global__ __launch_bounds__(512) void k_pscan(int* __restrict__ blkhist, int* __restrict__ base,
                                               int* __restrict__ cnt, int* __restrict__ row_ptr) {
    __shared__ int s[512];
    int j = threadIdx.x;
    int tot = 0;
    if (j < NT) {
        for (int b = 0; b < NB1; ++b) {                  // coalesced across j
            int v = blkhist[b * NT + j];
            blkhist[b * NT + j] = tot;
            tot += v;
        }
    }
    s[j] = (j < NT) ? tot : 0;
    __syncthreads();
    for (int st = 1; st < 512; st <<= 1) {
        int u = (j >= st) ? s[j - st] : 0;
        __syncthreads();
        s[j] += u;
        __syncthreads();
    }
    if (j < NT) {
        int bs = s[j] - tot;                             // exclusive bucket base
        base[j] = bs;
        cnt[j] = tot;
        for (int b = 0; b < NB1; ++b) blkhist[b * NT + j] += bs;
    }
    if (j == 0) row_ptr[N_NODES] = N_EDGES;
}

__global__ __launch_bounds__(256) void k_pscatter(const int* __restrict__ row, const int* __restrict__ col,
                                                  const float* __restrict__ val,
                                                  const int* __restrict__ blkhist, int2* __restrict__ part) {
    __shared__ int cur[NT];
    int b = blockIdx.x, t = threadIdx.x;
    for (int i = t; i < NT; i += 256) cur[i] = blkhist[b * NT + i];
    __syncthreads();
    int s = b * CHUNK, e = min(s + CHUNK, N_EDGES);
    for (int i = s + t; i < e; i += 256) {
        int r = row[i];
        int j = r >> 8;
        int p = atomicAdd(&cur[j], 1);
        part[p] = make_int2(((r & 255) << 24) | col[i], __float_as_int(val[i]));
    }
}

// Pass 4: per-bucket LDS counting sort -> final packed u32 CSR (col<<15 | q15(val)) + row_ptr.
__global__ __launch_bounds__(256) void k_sort(const int2* __restrict__ part, const int* __restrict__ cnt,
                                              const int* __restrict__ base, int* __restrict__ row_ptr,
                                              unsigned* __restrict__ csr) {
    __shared__ int hist[256];
    __shared__ int cur[256];
    int b = blockIdx.x, t = threadIdx.x;
    int n = cnt[b];
    int bb = base[b];
    const int2* sl = part + bb;
    hist[t] = 0;
    __syncthreads();
    for (int i = t; i < n; i += 256) atomicAdd(&hist[((unsigned)sl[i].x) >> 24], 1);
    __syncthreads();
    int v = hist[t];
    for (int st = 1; st < 256; st <<= 1) {
        int u = (t >= st) ? hist[t - st] : 0;
        __syncthreads();
        hist[t] += u;
        __syncthreads();
    }
    cur[t] = hist[t] - v;
    int grow = b * 256 + t;
    if (grow < N_NODES) row_ptr[grow] = bb + cur[t];
    __syncthreads();
    for (int i = t; i < n; i += 256) {
        int2 e = sl[i];
        int rl = ((unsigned)e.x) >> 24;
        int p = atomicAdd(&cur[rl], 1);
        unsigned c = (unsigned)(e.x & 0xFFFFFF);
        float vf = __int_as_float(e.y);
        int q = __float2int_rn(vf * 32768.0f);
        if (q > 32767) q = 32767;
        csr[bb + p] = (c << 15) | (unsigned)q;
    }
}

// ---------------- GEMM1: x[N,256] @ W1[256,32] -> support fp8 [N,32] ----------------
__global__ __launch_bounds__(256) void k_gemm1(const float* __restrict__ x, const float* __restrict__ W,
                                               unsigned char* __restrict__ out) {
    __shared__ float xsT[64][66];
    __shared__ __align__(16) float wc[64 * 32];
    int tid = threadIdx.x;
    int bn = blockIdx.x * 64;
    int tn = tid & 31;        // node pair: 2tn, 2tn+1
    int to = tid >> 5;        // out quad: 4to..4to+3
    float acc[2][4] = {};
    for (int kc = 0; kc < 4; ++kc) {
        int k0 = kc * 64;
        #pragma unroll
        for (int i = 0; i < 4; ++i) {
            int idx = i * 256 + tid;
            int n = idx >> 4;
            int k4 = (idx & 15) * 4;
            float4 v = make_float4(0.f, 0.f, 0.f, 0.f);
            if (bn + n < N_NODES)
                v = *reinterpret_cast<const float4*>(&x[(size_t)(bn + n) * 256 + k0 + k4]);
            xsT[k4 + 0][n] = v.x; xsT[k4 + 1][n] = v.y; xsT[k4 + 2][n] = v.z; xsT[k4 + 3][n] = v.w;
        }
        #pragma unroll
        for (int i = 0; i < 2; ++i) {
            int idx = i * 256 + tid;
            reinterpret_cast<float4*>(wc)[idx] =
                reinterpret_cast<const float4*>(W + (size_t)k0 * 32)[idx];
        }
        __syncthreads();
        #pragma unroll 8
        for (int k = 0; k < 64; ++k) {
            float2 a = *reinterpret_cast<const float2*>(&xsT[k][2 * tn]);
            float4 w = *reinterpret_cast<const float4*>(&wc[k * 32 + 4 * to]);
            acc[0][0] += a.x * w.x; acc[0][1] += a.x * w.y; acc[0][2] += a.x * w.z; acc[0][3] += a.x * w.w;
            acc[1][0] += a.y * w.x; acc[1][1] += a.y * w.y; acc[1][2] += a.y * w.z; acc[1][3] += a.y * w.w;
        }
        __syncthreads();
    }
    #pragma unroll
    for (int i = 0; i < 2; ++i) {
        int n = bn + 2 * tn + i;
        if (n < N_NODES) {
            unsigned r = pack4_fp8(acc[i][0], acc[i][1], acc[i][2], acc[i][3]);
            *reinterpret_cast<unsigned*>(&out[(size_t)n * 32 + 4 * to]) = r;
        }
    }
}

// ---------------- SpMM layer1: 4 lanes x uint2(8 fp8) per row, F=32 ----------------
__global__ __launch_bounds__(256, 8) void k_spmm1(const int* __restrict__ rp, const unsigned* __restrict__ csr,
                                                  const unsigned char* __restrict__ sup,
                                                  const float* __restrict__ bias,
                                                  unsigned char* __restrict__ out) {
    int gid = blockIdx.x * 256 + threadIdx.x;
    int n = gid >> 2;
    if (n >= N_NODES) return;
    int f8 = (gid & 3) * 8;
    int e0 = rp[n], e1 = rp[n + 1];
    float a0 = 0.f, a1 = 0.f, a2 = 0.f, a3 = 0.f, a4 = 0.f, a5 = 0.f, a6 = 0.f, a7 = 0.f;
    int e = e0;
    if ((e & 1) && e < e1) {
        unsigned ent = csr[e];
        float v = (float)(ent & 0x7FFF);
        uint2 u = *reinterpret_cast<const uint2*>(&sup[(size_t)(ent >> 15) * 32 + f8]);
        a0 += v * CVT(u.x, 0); a1 += v * CVT(u.x, 1); a2 += v * CVT(u.x, 2); a3 += v * CVT(u.x, 3);
        a4 += v * CVT(u.y, 0); a5 += v * CVT(u.y, 1); a6 += v * CVT(u.y, 2); a7 += v * CVT(u.y, 3);
        ++e;
    }
    for (; e + 1 < e1; e += 2) {
        uint2 p = *reinterpret_cast<const uint2*>(&csr[e]);
        uint2 u = *reinterpret_cast<const uint2*>(&sup[(size_t)(p.x >> 15) * 32 + f8]);
        uint2 w = *reinterpret_cast<const uint2*>(&sup[(size_t)(p.y >> 15) * 32 + f8]);
        float v0 = (float)(p.x & 0x7FFF), v1 = (float)(p.y & 0x7FFF);
        a0 += v0 * CVT(u.x, 0) + v1 * CVT(w.x, 0);
        a1 += v0 * CVT(u.x, 1) + v1 * CVT(w.x, 1);
        a2 += v0 * CVT(u.x, 2) + v1 * CVT(w.x, 2);
        a3 += v0 * CVT(u.x, 3) + v1 * CVT(w.x, 3);
        a4 += v0 * CVT(u.y, 0) + v1 * CVT(w.y, 0);
        a5 += v0 * CVT(u.y, 1) + v1 * CVT(w.y, 1);
        a6 += v0 * CVT(u.y, 2) + v1 * CVT(w.y, 2);
        a7 += v0 * CVT(u.y, 3) + v1 * CVT(w.y, 3);
    }
    if (e < e1) {
        unsigned ent = csr[e];
        float v = (float)(ent & 0x7FFF);
        uint2 u = *reinterpret_cast<const uint2*>(&sup[(size_t)(ent >> 15) * 32 + f8]);
        a0 += v * CVT(u.x, 0); a1 += v * CVT(u.x, 1); a2 += v * CVT(u.x, 2); a3 += v * CVT(u.x, 3);
        a4 += v * CVT(u.y, 0); a5 += v * CVT(u.y, 1); a6 += v * CVT(u.y, 2); a7 += v * CVT(u.y, 3);
    }
    const float sc = 1.0f / 32768.0f;
    uint2 r;
    r.x = pack4_fp8(fmaxf(a0 * sc + bias[f8 + 0], 0.f), fmaxf(a1 * sc + bias[f8 + 1], 0.f),
                    fmaxf(a2 * sc + bias[f8 + 2], 0.f), fmaxf(a3 * sc + bias[f8 + 3], 0.f));
    r.y = pack4_fp8(fmaxf(a4 * sc + bias[f8 + 4], 0.f), fmaxf(a5 * sc + bias[f8 + 5], 0.f),
                    fmaxf(a6 * sc + bias[f8 + 6], 0.f), fmaxf(a7 * sc + bias[f8 + 7], 0.f));
    *reinterpret_cast<uint2*>(&out[(size_t)n * 32 + f8]) = r;
}

// ---------------- layer2 fused: g2 = spmm(h1); h2 = relu(g2@W2+b2) fp8. 64 rows/block ----------------
__global__ __launch_bounds__(256, 8) void k_l2fused(const int* __restrict__ rp, const unsigned* __restrict__ csr,
                                                    const unsigned char* __restrict__ h1,
                                                    const float* __restrict__ W2, const float* __restrict__ b2,
                                                    unsigned char* __restrict__ h2) {
    __shared__ float w2s[32 * 48];
    __shared__ float b2s[48];
    __shared__ float g2s[64][33];
    int tid = threadIdx.x;
    for (int i = tid; i < 32 * 48; i += 256) w2s[i] = W2[i];
    if (tid < 48) b2s[tid] = b2[tid];
    int n0 = blockIdx.x * 64;
    int grp = tid >> 2;
    int f8 = (tid & 3) * 8;
    int n = n0 + grp;
    if (n < N_NODES) {
        int e0 = rp[n], e1 = rp[n + 1];
        float a0 = 0.f, a1 = 0.f, a2 = 0.f, a3 = 0.f, a4 = 0.f, a5 = 0.f, a6 = 0.f, a7 = 0.f;
        int e = e0;
        if ((e & 1) && e < e1) {
            unsigned ent = csr[e];
            float v = (float)(ent & 0x7FFF);
            uint2 u = *reinterpret_cast<const uint2*>(&h1[(size_t)(ent >> 15) * 32 + f8]);
            a0 += v * CVT(u.x, 0); a1 += v * CVT(u.x, 1); a2 += v * CVT(u.x, 2); a3 += v * CVT(u.x, 3);
            a4 += v * CVT(u.y, 0); a5 += v * CVT(u.y, 1); a6 += v * CVT(u.y, 2); a7 += v * CVT(u.y, 3);
            ++e;
        }
        for (; e + 1 < e1; e += 2) {
            uint2 p = *reinterpret_cast<const uint2*>(&csr[e]);
            uint2 u = *reinterpret_cast<const uint2*>(&h1[(size_t)(p.x >> 15) * 32 + f8]);
            uint2 w = *reinterpret_cast<const uint2*>(&h1[(size_t)(p.y >> 15) * 32 + f8]);
            float v0 = (float)(p.x & 0x7FFF), v1 = (float)(p.y & 0x7FFF);
            a0 += v0 * CVT(u.x, 0) + v1 * CVT(w.x, 0);
            a1 += v0 * CVT(u.x, 1) + v1 * CVT(w.x, 1);
            a2 += v0 * CVT(u.x, 2) + v1 * CVT(w.x, 2);
            a3 += v0 * CVT(u.x, 3) + v1 * CVT(w.x, 3);
            a4 += v0 * CVT(u.y, 0) + v1 * CVT(w.y, 0);
            a5 += v0 * CVT(u.y, 1) + v1 * CVT(w.y, 1);
            a6 += v0 * CVT(u.y, 2) + v1 * CVT(w.y, 2);
            a7 += v0 * CVT(u.y, 3) + v1 * CVT(w.y, 3);
        }
        if (e < e1) {
            unsigned ent = csr[e];
            float v = (float)(ent & 0x7FFF);
            uint2 u = *reinterpret_cast<const uint2*>(&h1[(size_t)(ent >> 15) * 32 + f8]);
            a0 += v * CVT(u.x, 0); a1 += v * CVT(u.x, 1); a2 += v * CVT(u.x, 2); a3 += v * CVT(u.x, 3);
            a4 += v * CVT(u.y, 0); a5 += v * CVT(u.y, 1); a6 += v * CVT(u.y, 2); a7 += v * CVT(u.y, 3);
        }
        const float sc = 1.0f / 32768.0f;
        g2s[grp][f8 + 0] = a0 * sc; g2s[grp][f8 + 1] = a1 * sc;
        g2s[grp][f8 + 2] = a2 * sc; g2s[grp][f8 + 3] = a3 * sc;
        g2s[grp][f8 + 4] = a4 * sc; g2s[grp][f8 + 5] = a5 * sc;
        g2s[grp][f8 + 6] = a6 * sc; g2s[grp][f8 + 7] = a7 * sc;
    }
    __syncthreads();
    #pragma unroll
    for (int pp = 0; pp < 12; ++pp) {
        int idx = pp * 256 + tid;
        int r = idx / 48;
        int m = idx - 48 * r;
        if (n0 + r < N_NODES) {
            float a = b2s[m];
            const float* g = g2s[r];
            #pragma unroll
            for (int k = 0; k < 32; ++k) a += g[k] * w2s[k * 48 + m];
            h2[(size_t)(n0 + r) * 48 + m] = f2q(fmaxf(a, 0.f));
        }
    }
}

// ---------------- layer3 fused: g3 = spmm(h2); relu(g3@W3+b3); pool partial. 40 rows/block ----------------
__global__ __launch_bounds__(256, 8) void k_l3fused(const int* __restrict__ rp, const unsigned* __restrict__ csr,
                                                    const unsigned char* __restrict__ h2,
                                                    const float* __restrict__ W3, const float* __restrict__ b3,
                                                    float* __restrict__ poolpart) {
    __shared__ float w3s[48 * 64];
    __shared__ float b3s[64];
    __shared__ float g3s[ROWS3][49];
    __shared__ float red[256];
    int tid = threadIdx.x;
    for (int i = tid; i < 48 * 64; i += 256) w3s[i] = W3[i];
    if (tid < 64) b3s[tid] = b3[tid];
    int grp = tid / 6;                        // row 0..39 for tid<240
    int f8 = (tid - grp * 6) * 8;             // 0,8,16,24,32,40
    int m = tid & 63;
    const float sc = 1.0f / 32768.0f;
    if (tid < 240) {
        int n = blockIdx.x * ROWS3 + grp;
        int e0 = rp[n], e1 = rp[n + 1];
        float a0 = 0.f, a1 = 0.f, a2 = 0.f, a3 = 0.f, a4 = 0.f, a5 = 0.f, a6 = 0.f, a7 = 0.f;
        int e = e0;
        if ((e & 1) && e < e1) {
            unsigned ent = csr[e];
            float v = (float)(ent & 0x7FFF);
            uint2 u = *reinterpret_cast<const uint2*>(&h2[(size_t)(ent >> 15) * 48 + f8]);
            a0 += v * CVT(u.x, 0); a1 += v * CVT(u.x, 1); a2 += v * CVT(u.x, 2); a3 += v * CVT(u.x, 3);
            a4 += v * CVT(u.y, 0); a5 += v * CVT(u.y, 1); a6 += v * CVT(u.y, 2); a7 += v * CVT(u.y, 3);
            ++e;
        }
        for (; e + 1 < e1; e += 2) {
            uint2 p = *reinterpret_cast<const uint2*>(&csr[e]);
            uint2 u = *reinterpret_cast<const uint2*>(&h2[(size_t)(p.x >> 15) * 48 + f8]);
            uint2 w = *reinterpret_cast<const uint2*>(&h2[(size_t)(p.y >> 15) * 48 + f8]);
            float v0 = (float)(p.x & 0x7FFF), v1 = (float)(p.y & 0x7FFF);
            a0 += v0 * CVT(u.x, 0) + v1 * CVT(w.x, 0);
            a1 += v0 * CVT(u.x, 1) + v1 * CVT(w.x, 1);
            a2 += v0 * CVT(u.x, 2) + v1 * CVT(w.x, 2);
            a3 += v0 * CVT(u.x, 3) + v1 * CVT(w.x, 3);
            a4 += v0 * CVT(u.y, 0) + v1 * CVT(w.y, 0);
            a5 += v0 * CVT(u.y, 1) + v1 * CVT(w.y, 1);
            a6 += v0 * CVT(u.y, 2) + v1 * CVT(w.y, 2);
            a7 += v0 * CVT(u.y, 3) + v1 * CVT(w.y, 3);
        }
        if (e < e1) {
            unsigned ent = csr[e];
            float v = (float)(ent & 0x7FFF);
            uint2 u = *reinterpret_cast<const uint2*>(&h2[(size_t)(ent >> 15) * 48 + f8]);
            a0 += v * CVT(u.x, 0); a1 += v * CVT(u.x, 1); a2 += v * CVT(u.x, 2); a3 += v * CVT(u.x, 3);
            a4 += v * CVT(u.y, 0); a5 += v * CVT(u.y, 1); a6 += v * CVT(u.y, 2); a7 += v * CVT(u.y, 3);
        }
        g3s[grp][f8 + 0] = a0 * sc; g3s[grp][f8 + 1] = a1 * sc;
        g3s[grp][f8 + 2] = a2 * sc; g3s[grp][f8 + 3] = a3 * sc;
        g3s[grp][f8 + 4] = a4 * sc; g3s[grp][f8 + 5] = a5 * sc;
        g3s[grp][f8 + 6] = a6 * sc; g3s[grp][f8 + 7] = a7 * sc;
    }
    __syncthreads();
    float poolacc = 0.f;
    #pragma unroll
    for (int pp = 0; pp < 10; ++pp) {
        int r = 4 * pp + (tid >> 6);
        float a = b3s[m];
        const float* gg = g3s[r];
        #pragma unroll
        for (int k = 0; k < 48; ++k) a += gg[k] * w3s[k * 64 + m];
        poolacc += fmaxf(a, 0.f);
    }
    red[tid] = poolacc;
    __syncthreads();
    if (tid < 64) {
        float s = red[tid] + red[tid + 64] + red[tid + 128] + red[tid + 192];
        poolpart[(size_t)blockIdx.x * 64 + tid] = s;
    }
}

// ---------------- pool reduce: poolpart[GRID3][64] -> pool[64] (64 blocks) ----------------
__global__ __launch_bounds__(256) void k_preduce(const float* __restrict__ poolpart,
                                                 float* __restrict__ pool) {
    __shared__ float red[256];
    int b = blockIdx.x, t = threadIdx.x;
    float s = 0.f;
    for (int j = t; j < GRID3; j += 256) s += poolpart[(size_t)j * 64 + b];
    red[t] = s;
    __syncthreads();
    for (int st = 128; st > 0; st >>= 1) {
        if (t < st) red[t] += red[t + st];
        __syncthreads();
    }
    if (t == 0) pool[b] = red[0];
}

// ---------------- head: mean -> FC1+relu -> FC2 -> softmax (tiny) ----------------
__global__ __launch_bounds__(64) void k_head(const float* __restrict__ pool,
                                             const float* __restrict__ fc1W, const float* __restrict__ fc1b,
                                             const float* __restrict__ fc2W, const float* __restrict__ fc2b,
                                             float* __restrict__ out) {
    __shared__ float pl[64];
    __shared__ float z[32];
    __shared__ float lg[2];
    int t = threadIdx.x;
    pl[t] = pool[t] * (1.0f / (float)N_NODES);
    __syncthreads();
    if (t < 32) {
        float a = fc1b[t];
        #pragma unroll
        for (int o = 0; o < 64; ++o) a += pl[o] * fc1W[o * 32 + t];
        z[t] = fmaxf(a, 0.f);
    }
    __syncthreads();
    if (t < 2) {
        float l = fc2b[t];
        #pragma unroll
        for (int j = 0; j < 32; ++j) l += z[j] * fc2W[j * 2 + t];
        lg[t] = l;
    }
    __syncthreads();
    if (t == 0) {
        float mx = fmaxf(lg[0], lg[1]);
        float e0 = __expf(lg[0] - mx), e1 = __expf(lg[1] - mx);
        float ss = e0 + e1;
        out[0] = e0 / ss;
        out[1] = e1 / ss;
    }
}

// ---------------- launch ----------------

extern "C" void kernel_launch(void* const* d_in, const int* in_sizes, int n_in,
                              void* d_out, int out_size, void* d_ws, size_t ws_size,
                              hipStream_t stream) {
    const float* x    = (const float*)d_in[0];
    const int*   row  = (const int*)d_in[1];
    const int*   col  = (const int*)d_in[2];
    const float* val  = (const float*)d_in[3];
    const float* W1   = (const float*)d_in[4];
    const float* b1   = (const float*)d_in[5];
    const float* W2   = (const float*)d_in[6];
    const float* b2   = (const float*)d_in[7];
    const float* W3   = (const float*)d_in[8];
    const float* b3   = (const float*)d_in[9];
    const float* fc1W = (const float*)d_in[10];
    const float* fc1b = (const float*)d_in[11];
    const float* fc2W = (const float*)d_in[12];
    const float* fc2b = (const float*)d_in[13];
    float* out = (float*)d_out;

    char* wsb = (char*)d_ws;
    size_t off = 0;
    auto alloc = [&](size_t bytes) {
        void* p = wsb + off;
        off += (bytes + 255) / 256 * 256;
        return p;
    };
    int*      blkhist  = (int*)alloc((size_t)NT * NB1 * 4);
    int*      base     = (int*)alloc((size_t)NT * 4);
    int*      cnt      = (int*)alloc((size_t)NT * 4);
    int*      row_ptr  = (int*)alloc((size_t)(N_NODES + 1) * 4);
    int2*     part     = (int2*)alloc((size_t)N_EDGES * 8);
    unsigned* csr      = (unsigned*)alloc((size_t)N_EDGES * 4);
    unsigned char* sup = (unsigned char*)alloc((size_t)N_NODES * 32);
    unsigned char* h1  = (unsigned char*)alloc((size_t)N_NODES * 32);
    unsigned char* h2  = (unsigned char*)alloc((size_t)N_NODES * 48);
    float* poolpart    = (float*)alloc((size_t)GRID3 * 64 * 4);
    float* pool        = (float*)alloc(64 * 4);

    // CSR build (no global atomics)
    k_phist<<<NB1, 256, 0, stream>>>(row, blkhist);
    k_pscan<<<1, 512, 0, stream>>>(blkhist, base, cnt, row_ptr);
    k_pscatter<<<NB1, 256, 0, stream>>>(row, col, val, blkhist, part);
    k_sort<<<NT, 256, 0, stream>>>(part, cnt, base, row_ptr, csr);

    // layer 1
    k_gemm1<<<(N_NODES + 63) / 64, 256, 0, stream>>>(x, W1, sup);
    k_spmm1<<<(N_NODES * 4 + 255) / 256, 256, 0, stream>>>(row_ptr, csr, sup, b1, h1);
    // layer 2 fused (64 rows/block)
    k_l2fused<<<(N_NODES + 63) / 64, 256, 0, stream>>>(row_ptr, csr, h1, W2, b2, h2);
    // layer 3 fused + pool partials (40 rows/block)
    k_l3fused<<<GRID3, 256, 0, stream>>>(row_ptr, csr, h2, W3, b3, poolpart);
    // pool reduce + head
    k_preduce<<<64, 256, 0, stream>>>(poolpart, pool);
    k_head<<<1, 64, 0, stream>>>(pool, fc1W, fc1b, fc2W, fc2b, out);
}

// Round 9
// 227.770 us; speedup vs baseline: 2.1854x; 1.0253x over previous
//
#include <hip/hip_runtime.h>
#include <hip/hip_bf16.h>

#define N_NODES 100000
#define N_EDGES 1600000

#define NT 391                               // row buckets of 256 rows
#define NB1 128                              // partition blocks
#define CHUNK ((N_EDGES + NB1 - 1) / NB1)    // 12500 edges per block
#define ROWS3 80                             // rows per l3fused block
#define GRID3 (N_NODES / ROWS3)              // 1250 (exact)

// ---------------- fp8 e4m3 helpers (HW converts, gfx950 OCP) ----------------
__device__ __forceinline__ unsigned char f2q(float f) {
    return (unsigned char)(__builtin_amdgcn_cvt_pk_fp8_f32(f, f, 0, false) & 0xFF);
}
__device__ __forceinline__ unsigned pack4_fp8(float a0, float a1, float a2, float a3) {
    int r = __builtin_amdgcn_cvt_pk_fp8_f32(a0, a1, 0, false);
    r = __builtin_amdgcn_cvt_pk_fp8_f32(a2, a3, r, true);
    return (unsigned)r;
}
#define CVT(u, s) __builtin_amdgcn_cvt_f32_fp8((u), (s))

// accumulate 16 fp8 features (uint4) * v into 16 accumulators
#define ACC16(A, U, V)                                                              \
    A[0]  += (V) * CVT((U).x, 0); A[1]  += (V) * CVT((U).x, 1);                     \
    A[2]  += (V) * CVT((U).x, 2); A[3]  += (V) * CVT((U).x, 3);                     \
    A[4]  += (V) * CVT((U).y, 0); A[5]  += (V) * CVT((U).y, 1);                     \
    A[6]  += (V) * CVT((U).y, 2); A[7]  += (V) * CVT((U).y, 3);                     \
    A[8]  += (V) * CVT((U).z, 0); A[9]  += (V) * CVT((U).z, 1);                     \
    A[10] += (V) * CVT((U).z, 2); A[11] += (V) * CVT((U).z, 3);                     \
    A[12] += (V) * CVT((U).w, 0); A[13] += (V) * CVT((U).w, 1);                     \
    A[14] += (V) * CVT((U).w, 2); A[15] += (V) * CVT((U).w, 3);

// ---------------- CSR build: contention-free two-pass bucket partition ----------------

__global__ __launch_bounds__(256) void k_phist(const int* __restrict__ row, int* __restrict__ blkhist) {
    __shared__ int h[NT];
    int b = blockIdx.x, t = threadIdx.x;
    for (int i = t; i < NT; i += 256) h[i] = 0;
    __syncthreads();
    int s = b * CHUNK, e = min(s + CHUNK, N_EDGES);
    for (int i = s + t; i < e; i += 256) atomicAdd(&h[row[i] >> 8], 1);
    __syncthreads();
    for (int i = t; i < NT; i += 256) blkhist[b * NT + i] = h[i];   // b-major
}

__global__ __launch_bounds__(512) void k_pscan(int* __restrict__ blkhist, int* __restrict__ base,
                                               int* __restrict__ cnt, int* __restrict__ row_ptr) {
    __shared__ int s[512];
    int j = threadIdx.x;
    int tot = 0;
    if (j < NT) {
        for (int b = 0; b < NB1; ++b) {                  // coalesced across j
            int v = blkhist[b * NT + j];
            blkhist[b * NT + j] = tot;
            tot += v;
        }
    }
    s[j] = (j < NT) ? tot : 0;
    __syncthreads();
    for (int st = 1; st < 512; st <<= 1) {
        int u = (j >= st) ? s[j - st] : 0;
        __syncthreads();
        s[j] += u;
        __syncthreads();
    }
    if (j < NT) {
        int bs = s[j] - tot;                             // exclusive bucket base
        base[j] = bs;
        cnt[j] = tot;
        for (int b = 0; b < NB1; ++b) blkhist[b * NT + j] += bs;
    }
    if (j == 0) row_ptr[N_NODES] = N_EDGES;
}

__global__ __launch_bounds__(256) void k_pscatter(const int* __restrict__ row, const int* __restrict__ col,
                                                  const float* __restrict__ val,
                                                  const int* __restrict__ blkhist, int2* __restrict__ part) {
    __shared__ int cur[NT];
    int b = blockIdx.x, t = threadIdx.x;
    for (int i = t; i < NT; i += 256) cur[i] = blkhist[b * NT + i];
    __syncthreads();
    int s = b * CHUNK, e = min(s + CHUNK, N_EDGES);
    for (int i = s + t; i < e; i += 256) {
        int r = row[i];
        int j = r >> 8;
        int p = atomicAdd(&cur[j], 1);
        part[p] = make_int2(((r & 255) << 24) | col[i], __float_as_int(val[i]));
    }
}

// Pass 4: per-bucket LDS counting sort -> final packed u32 CSR (col<<15 | q15(val)) + row_ptr.
__global__ __launch_bounds__(256) void k_sort(const int2* __restrict__ part, const int* __restrict__ cnt,
                                              const int* __restrict__ base, int* __restrict__ row_ptr,
                                              unsigned* __restrict__ csr) {
    __shared__ int hist[256];
    __shared__ int cur[256];
    int b = blockIdx.x, t = threadIdx.x;
    int n = cnt[b];
    int bb = base[b];
    const int2* sl = part + bb;
    hist[t] = 0;
    __syncthreads();
    for (int i = t; i < n; i += 256) atomicAdd(&hist[((unsigned)sl[i].x) >> 24], 1);
    __syncthreads();
    int v = hist[t];
    for (int st = 1; st < 256; st <<= 1) {
        int u = (t >= st) ? hist[t - st] : 0;
        __syncthreads();
        hist[t] += u;
        __syncthreads();
    }
    cur[t] = hist[t] - v;
    int grow = b * 256 + t;
    if (grow < N_NODES) row_ptr[grow] = bb + cur[t];
    __syncthreads();
    for (int i = t; i < n; i += 256) {
        int2 e = sl[i];
        int rl = ((unsigned)e.x) >> 24;
        int p = atomicAdd(&cur[rl], 1);
        unsigned c = (unsigned)(e.x & 0xFFFFFF);
        float vf = __int_as_float(e.y);
        int q = __float2int_rn(vf * 32768.0f);
        if (q > 32767) q = 32767;
        csr[bb + p] = (c << 15) | (unsigned)q;
    }
}

// ---------------- GEMM1: x[N,256] @ W1[256,32] -> support fp8 [N,32] ----------------
// Row-major xs (conflict-free stores); reads are 8-lane broadcasts (free).
__global__ __launch_bounds__(256) void k_gemm1(const float* __restrict__ x, const float* __restrict__ W,
                                               unsigned char* __restrict__ out) {
    __shared__ float xs[64][68];
    __shared__ __align__(16) float wc[64 * 32];
    int tid = threadIdx.x;
    int bn = blockIdx.x * 64;
    int nl = tid >> 3;        // node low: handles nodes nl and nl+32
    int o4 = (tid & 7) * 4;   // out quad
    float acc[2][4] = {};
    for (int kc = 0; kc < 4; ++kc) {
        int k0 = kc * 64;
        #pragma unroll
        for (int i = 0; i < 4; ++i) {
            int idx = i * 256 + tid;
            int n = idx >> 4;
            int k4 = (idx & 15) * 4;
            float4 v = make_float4(0.f, 0.f, 0.f, 0.f);
            if (bn + n < N_NODES)
                v = *reinterpret_cast<const float4*>(&x[(size_t)(bn + n) * 256 + k0 + k4]);
            *reinterpret_cast<float4*>(&xs[n][k4]) = v;
        }
        #pragma unroll
        for (int i = 0; i < 2; ++i) {
            int idx = i * 256 + tid;
            reinterpret_cast<float4*>(wc)[idx] =
                reinterpret_cast<const float4*>(W + (size_t)k0 * 32)[idx];
        }
        __syncthreads();
        #pragma unroll 8
        for (int k = 0; k < 64; ++k) {
            float a0 = xs[nl][k];
            float a1 = xs[nl + 32][k];
            float4 w = *reinterpret_cast<const float4*>(&wc[k * 32 + o4]);
            acc[0][0] += a0 * w.x; acc[0][1] += a0 * w.y; acc[0][2] += a0 * w.z; acc[0][3] += a0 * w.w;
            acc[1][0] += a1 * w.x; acc[1][1] += a1 * w.y; acc[1][2] += a1 * w.z; acc[1][3] += a1 * w.w;
        }
        __syncthreads();
    }
    #pragma unroll
    for (int i = 0; i < 2; ++i) {
        int n = bn + nl + 32 * i;
        if (n < N_NODES) {
            unsigned r = pack4_fp8(acc[i][0], acc[i][1], acc[i][2], acc[i][3]);
            *reinterpret_cast<unsigned*>(&out[(size_t)n * 32 + o4]) = r;
        }
    }
}

// ---------------- SpMM layer1: 2 lanes x uint4(16 fp8) per row, F=32 ----------------
__global__ __launch_bounds__(256, 8) void k_spmm1(const int* __restrict__ rp, const unsigned* __restrict__ csr,
                                                  const unsigned char* __restrict__ sup,
                                                  const float* __restrict__ bias,
                                                  unsigned char* __restrict__ out) {
    int gid = blockIdx.x * 256 + threadIdx.x;
    int n = gid >> 1;
    if (n >= N_NODES) return;
    int f16 = (gid & 1) * 16;
    int e0 = rp[n], e1 = rp[n + 1];
    float a[16] = {};
    int e = e0;
    if ((e & 1) && e < e1) {
        unsigned ent = csr[e];
        float v = (float)(ent & 0x7FFF);
        uint4 u = *reinterpret_cast<const uint4*>(&sup[(size_t)(ent >> 15) * 32 + f16]);
        ACC16(a, u, v)
        ++e;
    }
    for (; e + 1 < e1; e += 2) {
        uint2 p = *reinterpret_cast<const uint2*>(&csr[e]);
        uint4 u = *reinterpret_cast<const uint4*>(&sup[(size_t)(p.x >> 15) * 32 + f16]);
        uint4 w = *reinterpret_cast<const uint4*>(&sup[(size_t)(p.y >> 15) * 32 + f16]);
        float v0 = (float)(p.x & 0x7FFF), v1 = (float)(p.y & 0x7FFF);
        ACC16(a, u, v0)
        ACC16(a, w, v1)
    }
    if (e < e1) {
        unsigned ent = csr[e];
        float v = (float)(ent & 0x7FFF);
        uint4 u = *reinterpret_cast<const uint4*>(&sup[(size_t)(ent >> 15) * 32 + f16]);
        ACC16(a, u, v)
    }
    const float sc = 1.0f / 32768.0f;
    uint4 r;
    r.x = pack4_fp8(fmaxf(a[0] * sc + bias[f16 + 0], 0.f),  fmaxf(a[1] * sc + bias[f16 + 1], 0.f),
                    fmaxf(a[2] * sc + bias[f16 + 2], 0.f),  fmaxf(a[3] * sc + bias[f16 + 3], 0.f));
    r.y = pack4_fp8(fmaxf(a[4] * sc + bias[f16 + 4], 0.f),  fmaxf(a[5] * sc + bias[f16 + 5], 0.f),
                    fmaxf(a[6] * sc + bias[f16 + 6], 0.f),  fmaxf(a[7] * sc + bias[f16 + 7], 0.f));
    r.z = pack4_fp8(fmaxf(a[8] * sc + bias[f16 + 8], 0.f),  fmaxf(a[9] * sc + bias[f16 + 9], 0.f),
                    fmaxf(a[10] * sc + bias[f16 + 10], 0.f), fmaxf(a[11] * sc + bias[f16 + 11], 0.f));
    r.w = pack4_fp8(fmaxf(a[12] * sc + bias[f16 + 12], 0.f), fmaxf(a[13] * sc + bias[f16 + 13], 0.f),
                    fmaxf(a[14] * sc + bias[f16 + 14], 0.f), fmaxf(a[15] * sc + bias[f16 + 15], 0.f));
    *reinterpret_cast<uint4*>(&out[(size_t)n * 32 + f16]) = r;
}

// ---------------- layer2 fused: g2 = spmm(h1); h2 = relu(g2@W2+b2) fp8. 128 rows/block ----------------
__global__ __launch_bounds__(256, 8) void k_l2fused(const int* __restrict__ rp, const unsigned* __restrict__ csr,
                                                    const unsigned char* __restrict__ h1,
                                                    const float* __restrict__ W2, const float* __restrict__ b2,
                                                    unsigned char* __restrict__ h2) {
    __shared__ float w2s[32 * 48];
    __shared__ float b2s[48];
    __shared__ float g2s[128][33];
    int tid = threadIdx.x;
    for (int i = tid; i < 32 * 48; i += 256) w2s[i] = W2[i];
    if (tid < 48) b2s[tid] = b2[tid];
    int n0 = blockIdx.x * 128;
    int grp = tid >> 1;
    int f16 = (tid & 1) * 16;
    int n = n0 + grp;
    if (n < N_NODES) {
        int e0 = rp[n], e1 = rp[n + 1];
        float a[16] = {};
        int e = e0;
        if ((e & 1) && e < e1) {
            unsigned ent = csr[e];
            float v = (float)(ent & 0x7FFF);
            uint4 u = *reinterpret_cast<const uint4*>(&h1[(size_t)(ent >> 15) * 32 + f16]);
            ACC16(a, u, v)
            ++e;
        }
        for (; e + 1 < e1; e += 2) {
            uint2 p = *reinterpret_cast<const uint2*>(&csr[e]);
            uint4 u = *reinterpret_cast<const uint4*>(&h1[(size_t)(p.x >> 15) * 32 + f16]);
            uint4 w = *reinterpret_cast<const uint4*>(&h1[(size_t)(p.y >> 15) * 32 + f16]);
            float v0 = (float)(p.x & 0x7FFF), v1 = (float)(p.y & 0x7FFF);
            ACC16(a, u, v0)
            ACC16(a, w, v1)
        }
        if (e < e1) {
            unsigned ent = csr[e];
            float v = (float)(ent & 0x7FFF);
            uint4 u = *reinterpret_cast<const uint4*>(&h1[(size_t)(ent >> 15) * 32 + f16]);
            ACC16(a, u, v)
        }
        const float sc = 1.0f / 32768.0f;
        #pragma unroll
        for (int j = 0; j < 16; ++j) g2s[grp][f16 + j] = a[j] * sc;
    }
    __syncthreads();
    #pragma unroll
    for (int pp = 0; pp < 24; ++pp) {
        int idx = pp * 256 + tid;
        int r = idx / 48;
        int m = idx - 48 * r;
        if (n0 + r < N_NODES) {
            float a = b2s[m];
            const float* g = g2s[r];
            #pragma unroll
            for (int k = 0; k < 32; ++k) a += g[k] * w2s[k * 48 + m];
            h2[(size_t)(n0 + r) * 48 + m] = f2q(fmaxf(a, 0.f));
        }
    }
}

// ---------------- layer3 fused: g3 = spmm(h2); relu(g3@W3+b3); pool partial. 80 rows/block ----------------
__global__ __launch_bounds__(256, 8) void k_l3fused(const int* __restrict__ rp, const unsigned* __restrict__ csr,
                                                    const unsigned char* __restrict__ h2,
                                                    const float* __restrict__ W3, const float* __restrict__ b3,
                                                    float* __restrict__ poolpart) {
    __shared__ float w3s[48 * 64];
    __shared__ float b3s[64];
    __shared__ float g3s[ROWS3][49];
    __shared__ float red[256];
    int tid = threadIdx.x;
    for (int i = tid; i < 48 * 64; i += 256) w3s[i] = W3[i];
    if (tid < 64) b3s[tid] = b3[tid];
    int grp = tid / 3;                        // row 0..79 for tid<240
    int f16 = (tid - grp * 3) * 16;           // 0,16,32
    int m = tid & 63;
    const float sc = 1.0f / 32768.0f;
    if (tid < 240) {
        int n = blockIdx.x * ROWS3 + grp;
        int e0 = rp[n], e1 = rp[n + 1];
        float a[16] = {};
        int e = e0;
        if ((e & 1) && e < e1) {
            unsigned ent = csr[e];
            float v = (float)(ent & 0x7FFF);
            uint4 u = *reinterpret_cast<const uint4*>(&h2[(size_t)(ent >> 15) * 48 + f16]);
            ACC16(a, u, v)
            ++e;
        }
        for (; e + 1 < e1; e += 2) {
            uint2 p = *reinterpret_cast<const uint2*>(&csr[e]);
            uint4 u = *reinterpret_cast<const uint4*>(&h2[(size_t)(p.x >> 15) * 48 + f16]);
            uint4 w = *reinterpret_cast<const uint4*>(&h2[(size_t)(p.y >> 15) * 48 + f16]);
            float v0 = (float)(p.x & 0x7FFF), v1 = (float)(p.y & 0x7FFF);
            ACC16(a, u, v0)
            ACC16(a, w, v1)
        }
        if (e < e1) {
            unsigned ent = csr[e];
            float v = (float)(ent & 0x7FFF);
            uint4 u = *reinterpret_cast<const uint4*>(&h2[(size_t)(ent >> 15) * 48 + f16]);
            ACC16(a, u, v)
        }
        #pragma unroll
        for (int j = 0; j < 16; ++j) g3s[grp][f16 + j] = a[j] * sc;
    }
    __syncthreads();
    float poolacc = 0.f;
    #pragma unroll
    for (int pp = 0; pp < 20; ++pp) {
        int r = 4 * pp + (tid >> 6);
        float a = b3s[m];
        const float* gg = g3s[r];
        #pragma unroll
        for (int k = 0; k < 48; ++k) a += gg[k] * w3s[k * 64 + m];
        poolacc += fmaxf(a, 0.f);
    }
    red[tid] = poolacc;
    __syncthreads();
    if (tid < 64) {
        float s = red[tid] + red[tid + 64] + red[tid + 128] + red[tid + 192];
        poolpart[(size_t)blockIdx.x * 64 + tid] = s;
    }
}

// ---------------- pool reduce: poolpart[GRID3][64] -> pool[64] (64 blocks) ----------------
__global__ __launch_bounds__(256) void k_preduce(const float* __restrict__ poolpart,
                                                 float* __restrict__ pool) {
    __shared__ float red[256];
    int b = blockIdx.x, t = threadIdx.x;
    float s = 0.f;
    for (int j = t; j < GRID3; j += 256) s += poolpart[(size_t)j * 64 + b];
    red[t] = s;
    __syncthreads();
    for (int st = 128; st > 0; st >>= 1) {
        if (t < st) red[t] += red[t + st];
        __syncthreads();
    }
    if (t == 0) pool[b] = red[0];
}

// ---------------- head: mean -> FC1+relu -> FC2 -> softmax (tiny) ----------------
__global__ __launch_bounds__(64) void k_head(const float* __restrict__ pool,
                                             const float* __restrict__ fc1W, const float* __restrict__ fc1b,
                                             const float* __restrict__ fc2W, const float* __restrict__ fc2b,
                                             float* __restrict__ out) {
    __shared__ float pl[64];
    __shared__ float z[32];
    __shared__ float lg[2];
    int t = threadIdx.x;
    pl[t] = pool[t] * (1.0f / (float)N_NODES);
    __syncthreads();
    if (t < 32) {
        float a = fc1b[t];
        #pragma unroll
        for (int o = 0; o < 64; ++o) a += pl[o] * fc1W[o * 32 + t];
        z[t] = fmaxf(a, 0.f);
    }
    __syncthreads();
    if (t < 2) {
        float l = fc2b[t];
        #pragma unroll
        for (int j = 0; j < 32; ++j) l += z[j] * fc2W[j * 2 + t];
        lg[t] = l;
    }
    __syncthreads();
    if (t == 0) {
        float mx = fmaxf(lg[0], lg[1]);
        float e0 = __expf(lg[0] - mx), e1 = __expf(lg[1] - mx);
        float ss = e0 + e1;
        out[0] = e0 / ss;
        out[1] = e1 / ss;
    }
}

// ---------------- launch ----------------

extern "C" void kernel_launch(void* const* d_in, const int* in_sizes, int n_in,
                              void* d_out, int out_size, void* d_ws, size_t ws_size,
                              hipStream_t stream) {
    const float* x    = (const float*)d_in[0];
    const int*   row  = (const int*)d_in[1];
    const int*   col  = (const int*)d_in[2];
    const float* val  = (const float*)d_in[3];
    const float* W1   = (const float*)d_in[4];
    const float* b1   = (const float*)d_in[5];
    const float* W2   = (const float*)d_in[6];
    const float* b2   = (const float*)d_in[7];
    const float* W3   = (const float*)d_in[8];
    const float* b3   = (const float*)d_in[9];
    const float* fc1W = (const float*)d_in[10];
    const float* fc1b = (const float*)d_in[11];
    const float* fc2W = (const float*)d_in[12];
    const float* fc2b = (const float*)d_in[13];
    float* out = (float*)d_out;

    char* wsb = (char*)d_ws;
    size_t off = 0;
    auto alloc = [&](size_t bytes) {
        void* p = wsb + off;
        off += (bytes + 255) / 256 * 256;
        return p;
    };
    int*      blkhist  = (int*)alloc((size_t)NT * NB1 * 4);
    int*      base     = (int*)alloc((size_t)NT * 4);
    int*      cnt      = (int*)alloc((size_t)NT * 4);
    int*      row_ptr  = (int*)alloc((size_t)(N_NODES + 1) * 4);
    int2*     part     = (int2*)alloc((size_t)N_EDGES * 8);
    unsigned* csr      = (unsigned*)alloc((size_t)N_EDGES * 4);
    unsigned char* sup = (unsigned char*)alloc((size_t)N_NODES * 32);
    unsigned char* h1  = (unsigned char*)alloc((size_t)N_NODES * 32);
    unsigned char* h2  = (unsigned char*)alloc((size_t)N_NODES * 48);
    float* poolpart    = (float*)alloc((size_t)GRID3 * 64 * 4);
    float* pool        = (float*)alloc(64 * 4);

    // CSR build (no global atomics)
    k_phist<<<NB1, 256, 0, stream>>>(row, blkhist);
    k_pscan<<<1, 512, 0, stream>>>(blkhist, base, cnt, row_ptr);
    k_pscatter<<<NB1, 256, 0, stream>>>(row, col, val, blkhist, part);
    k_sort<<<NT, 256, 0, stream>>>(part, cnt, base, row_ptr, csr);

    // layer 1
    k_gemm1<<<(N_NODES + 63) / 64, 256, 0, stream>>>(x, W1, sup);
    k_spmm1<<<(N_NODES * 2 + 255) / 256, 256, 0, stream>>>(row_ptr, csr, sup, b1, h1);
    // layer 2 fused (128 rows/block)
    k_l2fused<<<(N_NODES + 127) / 128, 256, 0, stream>>>(row_ptr, csr, h1, W2, b2, h2);
    // layer 3 fused + pool partials (80 rows/block)
    k_l3fused<<<GRID3, 256, 0, stream>>>(row_ptr, csr, h2, W3, b3, poolpart);
    // pool reduce + head
    k_preduce<<<64, 256, 0, stream>>>(poolpart, pool);
    k_head<<<1, 64, 0, stream>>>(pool, fc1W, fc1b, fc2W, fc2b, out);
}

// Round 10
// 214.056 us; speedup vs baseline: 2.3254x; 1.0641x over previous
//
#include <hip/hip_runtime.h>
#include <hip/hip_bf16.h>

#define N_NODES 100000
#define N_EDGES 1600000

#define NT 391                               // row buckets of 256 rows
#define NB1 128                              // partition blocks
#define CHUNK ((N_EDGES + NB1 - 1) / NB1)    // 12500 edges per block
#define ROWS3 80                             // rows per l3fused block
#define GRID3 (N_NODES / ROWS3)              // 1250 (exact)

// ---------------- fp8 e4m3 helpers (HW converts, gfx950 OCP) ----------------
__device__ __forceinline__ unsigned char f2q(float f) {
    return (unsigned char)(__builtin_amdgcn_cvt_pk_fp8_f32(f, f, 0, false) & 0xFF);
}
__device__ __forceinline__ unsigned pack4_fp8(float a0, float a1, float a2, float a3) {
    int r = __builtin_amdgcn_cvt_pk_fp8_f32(a0, a1, 0, false);
    r = __builtin_amdgcn_cvt_pk_fp8_f32(a2, a3, r, true);
    return (unsigned)r;
}
#define CVT(u, s) __builtin_amdgcn_cvt_f32_fp8((u), (s))

// accumulate 16 fp8 features (uint4) * v into 16 accumulators
#define ACC16(A, U, V)                                                              \
    A[0]  += (V) * CVT((U).x, 0); A[1]  += (V) * CVT((U).x, 1);                     \
    A[2]  += (V) * CVT((U).x, 2); A[3]  += (V) * CVT((U).x, 3);                     \
    A[4]  += (V) * CVT((U).y, 0); A[5]  += (V) * CVT((U).y, 1);                     \
    A[6]  += (V) * CVT((U).y, 2); A[7]  += (V) * CVT((U).y, 3);                     \
    A[8]  += (V) * CVT((U).z, 0); A[9]  += (V) * CVT((U).z, 1);                     \
    A[10] += (V) * CVT((U).z, 2); A[11] += (V) * CVT((U).z, 3);                     \
    A[12] += (V) * CVT((U).w, 0); A[13] += (V) * CVT((U).w, 1);                     \
    A[14] += (V) * CVT((U).w, 2); A[15] += (V) * CVT((U).w, 3);

// ---------------- CSR build: contention-free partition, parallel scans ----------------

// Pass 1: per-block LDS histogram -> blkhist[j][b] (bucket-major).
__global__ __launch_bounds__(256) void k_phist(const int* __restrict__ row, int* __restrict__ blkhist) {
    __shared__ int h[NT];
    int b = blockIdx.x, t = threadIdx.x;
    for (int i = t; i < NT; i += 256) h[i] = 0;
    __syncthreads();
    int s = b * CHUNK, e = min(s + CHUNK, N_EDGES);
    for (int i = s + t; i < e; i += 256) atomicAdd(&h[row[i] >> 8], 1);
    __syncthreads();
    for (int i = t; i < NT; i += 256) blkhist[i * NB1 + b] = h[i];
}

// Pass 2a: per-bucket parallel scan over the 128 block partials (391 blocks).
__global__ __launch_bounds__(128) void k_bscan1(int* __restrict__ blkhist, int* __restrict__ cnt) {
    __shared__ int s[128];
    int j = blockIdx.x, t = threadIdx.x;
    int v = blkhist[j * NB1 + t];
    s[t] = v;
    __syncthreads();
    #pragma unroll
    for (int st = 1; st < 128; st <<= 1) {
        int u = (t >= st) ? s[t - st] : 0;
        __syncthreads();
        s[t] += u;
        __syncthreads();
    }
    blkhist[j * NB1 + t] = s[t] - v;          // exclusive within bucket
    if (t == 127) cnt[j] = s[127];
}

// Pass 2b: scan the 391 bucket totals -> base (1 tiny block).
__global__ __launch_bounds__(512) void k_bscan2(const int* __restrict__ cnt, int* __restrict__ base,
                                                int* __restrict__ row_ptr) {
    __shared__ int s[512];
    int j = threadIdx.x;
    int v = (j < NT) ? cnt[j] : 0;
    s[j] = v;
    __syncthreads();
    for (int st = 1; st < 512; st <<= 1) {
        int u = (j >= st) ? s[j - st] : 0;
        __syncthreads();
        s[j] += u;
        __syncthreads();
    }
    if (j < NT) base[j] = s[j] - v;
    if (j == 0) row_ptr[N_NODES] = N_EDGES;
}

// Pass 3: scatter each edge to its exact bucket slot (LDS cursors = blkhist + base).
__global__ __launch_bounds__(256) void k_pscatter(const int* __restrict__ row, const int* __restrict__ col,
                                                  const float* __restrict__ val,
                                                  const int* __restrict__ blkhist, const int* __restrict__ base,
                                                  int2* __restrict__ part) {
    __shared__ int cur[NT];
    int b = blockIdx.x, t = threadIdx.x;
    for (int i = t; i < NT; i += 256) cur[i] = blkhist[i * NB1 + b] + base[i];
    __syncthreads();
    int s = b * CHUNK, e = min(s + CHUNK, N_EDGES);
    for (int i = s + t; i < e; i += 256) {
        int r = row[i];
        int j = r >> 8;
        int p = atomicAdd(&cur[j], 1);
        part[p] = make_int2(((r & 255) << 24) | col[i], __float_as_int(val[i]));
    }
}

// Pass 4: per-bucket LDS counting sort -> final packed u32 CSR (col<<15 | q15(val)) + row_ptr.
__global__ __launch_bounds__(256) void k_sort(const int2* __restrict__ part, const int* __restrict__ cnt,
                                              const int* __restrict__ base, int* __restrict__ row_ptr,
                                              unsigned* __restrict__ csr) {
    __shared__ int hist[256];
    __shared__ int cur[256];
    int b = blockIdx.x, t = threadIdx.x;
    int n = cnt[b];
    int bb = base[b];
    const int2* sl = part + bb;
    hist[t] = 0;
    __syncthreads();
    for (int i = t; i < n; i += 256) atomicAdd(&hist[((unsigned)sl[i].x) >> 24], 1);
    __syncthreads();
    int v = hist[t];
    for (int st = 1; st < 256; st <<= 1) {
        int u = (t >= st) ? hist[t - st] : 0;
        __syncthreads();
        hist[t] += u;
        __syncthreads();
    }
    cur[t] = hist[t] - v;
    int grow = b * 256 + t;
    if (grow < N_NODES) row_ptr[grow] = bb + cur[t];
    __syncthreads();
    for (int i = t; i < n; i += 256) {
        int2 e = sl[i];
        int rl = ((unsigned)e.x) >> 24;
        int p = atomicAdd(&cur[rl], 1);
        unsigned c = (unsigned)(e.x & 0xFFFFFF);
        float vf = __int_as_float(e.y);
        int q = __float2int_rn(vf * 32768.0f);
        if (q > 32767) q = 32767;
        csr[bb + p] = (c << 15) | (unsigned)q;
    }
}

// ---------------- GEMM1: x[N,256] @ W1[256,32] -> support fp8 [N,32] ----------------
__global__ __launch_bounds__(256) void k_gemm1(const float* __restrict__ x, const float* __restrict__ W,
                                               unsigned char* __restrict__ out) {
    __shared__ float xs[64][68];
    __shared__ __align__(16) float wc[64 * 32];
    int tid = threadIdx.x;
    int bn = blockIdx.x * 64;
    int nl = tid >> 3;        // node low: handles nodes nl and nl+32
    int o4 = (tid & 7) * 4;   // out quad
    float acc[2][4] = {};
    for (int kc = 0; kc < 4; ++kc) {
        int k0 = kc * 64;
        #pragma unroll
        for (int i = 0; i < 4; ++i) {
            int idx = i * 256 + tid;
            int n = idx >> 4;
            int k4 = (idx & 15) * 4;
            float4 v = make_float4(0.f, 0.f, 0.f, 0.f);
            if (bn + n < N_NODES)
                v = *reinterpret_cast<const float4*>(&x[(size_t)(bn + n) * 256 + k0 + k4]);
            *reinterpret_cast<float4*>(&xs[n][k4]) = v;
        }
        #pragma unroll
        for (int i = 0; i < 2; ++i) {
            int idx = i * 256 + tid;
            reinterpret_cast<float4*>(wc)[idx] =
                reinterpret_cast<const float4*>(W + (size_t)k0 * 32)[idx];
        }
        __syncthreads();
        #pragma unroll 8
        for (int k = 0; k < 64; ++k) {
            float a0 = xs[nl][k];
            float a1 = xs[nl + 32][k];
            float4 w = *reinterpret_cast<const float4*>(&wc[k * 32 + o4]);
            acc[0][0] += a0 * w.x; acc[0][1] += a0 * w.y; acc[0][2] += a0 * w.z; acc[0][3] += a0 * w.w;
            acc[1][0] += a1 * w.x; acc[1][1] += a1 * w.y; acc[1][2] += a1 * w.z; acc[1][3] += a1 * w.w;
        }
        __syncthreads();
    }
    #pragma unroll
    for (int i = 0; i < 2; ++i) {
        int n = bn + nl + 32 * i;
        if (n < N_NODES) {
            unsigned r = pack4_fp8(acc[i][0], acc[i][1], acc[i][2], acc[i][3]);
            *reinterpret_cast<unsigned*>(&out[(size_t)n * 32 + o4]) = r;
        }
    }
}

// ---------------- SpMM layer1: 2 lanes x uint4(16 fp8) per row, F=32 ----------------
__global__ __launch_bounds__(256, 8) void k_spmm1(const int* __restrict__ rp, const unsigned* __restrict__ csr,
                                                  const unsigned char* __restrict__ sup,
                                                  const float* __restrict__ bias,
                                                  unsigned char* __restrict__ out) {
    int gid = blockIdx.x * 256 + threadIdx.x;
    int n = gid >> 1;
    if (n >= N_NODES) return;
    int f16 = (gid & 1) * 16;
    int e0 = rp[n], e1 = rp[n + 1];
    float a[16] = {};
    int e = e0;
    if ((e & 1) && e < e1) {
        unsigned ent = csr[e];
        float v = (float)(ent & 0x7FFF);
        uint4 u = *reinterpret_cast<const uint4*>(&sup[(size_t)(ent >> 15) * 32 + f16]);
        ACC16(a, u, v)
        ++e;
    }
    for (; e + 1 < e1; e += 2) {
        uint2 p = *reinterpret_cast<const uint2*>(&csr[e]);
        uint4 u = *reinterpret_cast<const uint4*>(&sup[(size_t)(p.x >> 15) * 32 + f16]);
        uint4 w = *reinterpret_cast<const uint4*>(&sup[(size_t)(p.y >> 15) * 32 + f16]);
        float v0 = (float)(p.x & 0x7FFF), v1 = (float)(p.y & 0x7FFF);
        ACC16(a, u, v0)
        ACC16(a, w, v1)
    }
    if (e < e1) {
        unsigned ent = csr[e];
        float v = (float)(ent & 0x7FFF);
        uint4 u = *reinterpret_cast<const uint4*>(&sup[(size_t)(ent >> 15) * 32 + f16]);
        ACC16(a, u, v)
    }
    const float sc = 1.0f / 32768.0f;
    uint4 r;
    r.x = pack4_fp8(fmaxf(a[0] * sc + bias[f16 + 0], 0.f),  fmaxf(a[1] * sc + bias[f16 + 1], 0.f),
                    fmaxf(a[2] * sc + bias[f16 + 2], 0.f),  fmaxf(a[3] * sc + bias[f16 + 3], 0.f));
    r.y = pack4_fp8(fmaxf(a[4] * sc + bias[f16 + 4], 0.f),  fmaxf(a[5] * sc + bias[f16 + 5], 0.f),
                    fmaxf(a[6] * sc + bias[f16 + 6], 0.f),  fmaxf(a[7] * sc + bias[f16 + 7], 0.f));
    r.z = pack4_fp8(fmaxf(a[8] * sc + bias[f16 + 8], 0.f),  fmaxf(a[9] * sc + bias[f16 + 9], 0.f),
                    fmaxf(a[10] * sc + bias[f16 + 10], 0.f), fmaxf(a[11] * sc + bias[f16 + 11], 0.f));
    r.w = pack4_fp8(fmaxf(a[12] * sc + bias[f16 + 12], 0.f), fmaxf(a[13] * sc + bias[f16 + 13], 0.f),
                    fmaxf(a[14] * sc + bias[f16 + 14], 0.f), fmaxf(a[15] * sc + bias[f16 + 15], 0.f));
    *reinterpret_cast<uint4*>(&out[(size_t)n * 32 + f16]) = r;
}

// ---------------- layer2 fused: g2 = spmm(h1); h2 = relu(g2@W2+b2) fp8. 128 rows/block ----------------
__global__ __launch_bounds__(256, 8) void k_l2fused(const int* __restrict__ rp, const unsigned* __restrict__ csr,
                                                    const unsigned char* __restrict__ h1,
                                                    const float* __restrict__ W2, const float* __restrict__ b2,
                                                    unsigned char* __restrict__ h2) {
    __shared__ float w2s[32 * 48];
    __shared__ float b2s[48];
    __shared__ float g2s[128][33];
    int tid = threadIdx.x;
    for (int i = tid; i < 32 * 48; i += 256) w2s[i] = W2[i];
    if (tid < 48) b2s[tid] = b2[tid];
    int n0 = blockIdx.x * 128;
    int grp = tid >> 1;
    int f16 = (tid & 1) * 16;
    int n = n0 + grp;
    if (n < N_NODES) {
        int e0 = rp[n], e1 = rp[n + 1];
        float a[16] = {};
        int e = e0;
        if ((e & 1) && e < e1) {
            unsigned ent = csr[e];
            float v = (float)(ent & 0x7FFF);
            uint4 u = *reinterpret_cast<const uint4*>(&h1[(size_t)(ent >> 15) * 32 + f16]);
            ACC16(a, u, v)
            ++e;
        }
        for (; e + 1 < e1; e += 2) {
            uint2 p = *reinterpret_cast<const uint2*>(&csr[e]);
            uint4 u = *reinterpret_cast<const uint4*>(&h1[(size_t)(p.x >> 15) * 32 + f16]);
            uint4 w = *reinterpret_cast<const uint4*>(&h1[(size_t)(p.y >> 15) * 32 + f16]);
            float v0 = (float)(p.x & 0x7FFF), v1 = (float)(p.y & 0x7FFF);
            ACC16(a, u, v0)
            ACC16(a, w, v1)
        }
        if (e < e1) {
            unsigned ent = csr[e];
            float v = (float)(ent & 0x7FFF);
            uint4 u = *reinterpret_cast<const uint4*>(&h1[(size_t)(ent >> 15) * 32 + f16]);
            ACC16(a, u, v)
        }
        const float sc = 1.0f / 32768.0f;
        #pragma unroll
        for (int j = 0; j < 16; ++j) g2s[grp][f16 + j] = a[j] * sc;
    }
    __syncthreads();
    #pragma unroll
    for (int pp = 0; pp < 24; ++pp) {
        int idx = pp * 256 + tid;
        int r = idx / 48;
        int m = idx - 48 * r;
        if (n0 + r < N_NODES) {
            float a = b2s[m];
            const float* g = g2s[r];
            #pragma unroll
            for (int k = 0; k < 32; ++k) a += g[k] * w2s[k * 48 + m];
            h2[(size_t)(n0 + r) * 48 + m] = f2q(fmaxf(a, 0.f));
        }
    }
}

// ---------------- layer3 fused: g3 = spmm(h2); relu(g3@W3+b3); pool partial. 80 rows/block ----------------
__global__ __launch_bounds__(256, 8) void k_l3fused(const int* __restrict__ rp, const unsigned* __restrict__ csr,
                                                    const unsigned char* __restrict__ h2,
                                                    const float* __restrict__ W3, const float* __restrict__ b3,
                                                    float* __restrict__ poolpart) {
    __shared__ float w3s[48 * 64];
    __shared__ float b3s[64];
    __shared__ float g3s[ROWS3][49];
    __shared__ float red[256];
    int tid = threadIdx.x;
    for (int i = tid; i < 48 * 64; i += 256) w3s[i] = W3[i];
    if (tid < 64) b3s[tid] = b3[tid];
    int grp = tid / 3;                        // row 0..79 for tid<240
    int f16 = (tid - grp * 3) * 16;           // 0,16,32
    int m = tid & 63;
    const float sc = 1.0f / 32768.0f;
    if (tid < 240) {
        int n = blockIdx.x * ROWS3 + grp;
        int e0 = rp[n], e1 = rp[n + 1];
        float a[16] = {};
        int e = e0;
        if ((e & 1) && e < e1) {
            unsigned ent = csr[e];
            float v = (float)(ent & 0x7FFF);
            uint4 u = *reinterpret_cast<const uint4*>(&h2[(size_t)(ent >> 15) * 48 + f16]);
            ACC16(a, u, v)
            ++e;
        }
        for (; e + 1 < e1; e += 2) {
            uint2 p = *reinterpret_cast<const uint2*>(&csr[e]);
            uint4 u = *reinterpret_cast<const uint4*>(&h2[(size_t)(p.x >> 15) * 48 + f16]);
            uint4 w = *reinterpret_cast<const uint4*>(&h2[(size_t)(p.y >> 15) * 48 + f16]);
            float v0 = (float)(p.x & 0x7FFF), v1 = (float)(p.y & 0x7FFF);
            ACC16(a, u, v0)
            ACC16(a, w, v1)
        }
        if (e < e1) {
            unsigned ent = csr[e];
            float v = (float)(ent & 0x7FFF);
            uint4 u = *reinterpret_cast<const uint4*>(&h2[(size_t)(ent >> 15) * 48 + f16]);
            ACC16(a, u, v)
        }
        #pragma unroll
        for (int j = 0; j < 16; ++j) g3s[grp][f16 + j] = a[j] * sc;
    }
    __syncthreads();
    float poolacc = 0.f;
    #pragma unroll
    for (int pp = 0; pp < 20; ++pp) {
        int r = 4 * pp + (tid >> 6);
        float a = b3s[m];
        const float* gg = g3s[r];
        #pragma unroll
        for (int k = 0; k < 48; ++k) a += gg[k] * w3s[k * 64 + m];
        poolacc += fmaxf(a, 0.f);
    }
    red[tid] = poolacc;
    __syncthreads();
    if (tid < 64) {
        float s = red[tid] + red[tid + 64] + red[tid + 128] + red[tid + 192];
        poolpart[(size_t)blockIdx.x * 64 + tid] = s;
    }
}

// ---------------- pool reduce: poolpart[GRID3][64] -> pool[64] (64 blocks) ----------------
__global__ __launch_bounds__(256) void k_preduce(const float* __restrict__ poolpart,
                                                 float* __restrict__ pool) {
    __shared__ float red[256];
    int b = blockIdx.x, t = threadIdx.x;
    float s = 0.f;
    for (int j = t; j < GRID3; j += 256) s += poolpart[(size_t)j * 64 + b];
    red[t] = s;
    __syncthreads();
    for (int st = 128; st > 0; st >>= 1) {
        if (t < st) red[t] += red[t + st];
        __syncthreads();
    }
    if (t == 0) pool[b] = red[0];
}

// ---------------- head: mean -> FC1+relu -> FC2 -> softmax (tiny) ----------------
__global__ __launch_bounds__(64) void k_head(const float* __restrict__ pool,
                                             const float* __restrict__ fc1W, const float* __restrict__ fc1b,
                                             const float* __restrict__ fc2W, const float* __restrict__ fc2b,
                                             float* __restrict__ out) {
    __shared__ float pl[64];
    __shared__ float z[32];
    __shared__ float lg[2];
    int t = threadIdx.x;
    pl[t] = pool[t] * (1.0f / (float)N_NODES);
    __syncthreads();
    if (t < 32) {
        float a = fc1b[t];
        #pragma unroll
        for (int o = 0; o < 64; ++o) a += pl[o] * fc1W[o * 32 + t];
        z[t] = fmaxf(a, 0.f);
    }
    __syncthreads();
    if (t < 2) {
        float l = fc2b[t];
        #pragma unroll
        for (int j = 0; j < 32; ++j) l += z[j] * fc2W[j * 2 + t];
        lg[t] = l;
    }
    __syncthreads();
    if (t == 0) {
        float mx = fmaxf(lg[0], lg[1]);
        float e0 = __expf(lg[0] - mx), e1 = __expf(lg[1] - mx);
        float ss = e0 + e1;
        out[0] = e0 / ss;
        out[1] = e1 / ss;
    }
}

// ---------------- launch ----------------

extern "C" void kernel_launch(void* const* d_in, const int* in_sizes, int n_in,
                              void* d_out, int out_size, void* d_ws, size_t ws_size,
                              hipStream_t stream) {
    const float* x    = (const float*)d_in[0];
    const int*   row  = (const int*)d_in[1];
    const int*   col  = (const int*)d_in[2];
    const float* val  = (const float*)d_in[3];
    const float* W1   = (const float*)d_in[4];
    const float* b1   = (const float*)d_in[5];
    const float* W2   = (const float*)d_in[6];
    const float* b2   = (const float*)d_in[7];
    const float* W3   = (const float*)d_in[8];
    const float* b3   = (const float*)d_in[9];
    const float* fc1W = (const float*)d_in[10];
    const float* fc1b = (const float*)d_in[11];
    const float* fc2W = (const float*)d_in[12];
    const float* fc2b = (const float*)d_in[13];
    float* out = (float*)d_out;

    char* wsb = (char*)d_ws;
    size_t off = 0;
    auto alloc = [&](size_t bytes) {
        void* p = wsb + off;
        off += (bytes + 255) / 256 * 256;
        return p;
    };
    int*      blkhist  = (int*)alloc((size_t)NT * NB1 * 4);
    int*      base     = (int*)alloc((size_t)NT * 4);
    int*      cnt      = (int*)alloc((size_t)NT * 4);
    int*      row_ptr  = (int*)alloc((size_t)(N_NODES + 1) * 4);
    int2*     part     = (int2*)alloc((size_t)N_EDGES * 8);
    unsigned* csr      = (unsigned*)alloc((size_t)N_EDGES * 4);
    unsigned char* sup = (unsigned char*)alloc((size_t)N_NODES * 32);
    unsigned char* h1  = (unsigned char*)alloc((size_t)N_NODES * 32);
    unsigned char* h2  = (unsigned char*)alloc((size_t)N_NODES * 48);
    float* poolpart    = (float*)alloc((size_t)GRID3 * 64 * 4);
    float* pool        = (float*)alloc(64 * 4);

    // CSR build (no global atomics, fully parallel scans)
    k_phist<<<NB1, 256, 0, stream>>>(row, blkhist);
    k_bscan1<<<NT, 128, 0, stream>>>(blkhist, cnt);
    k_bscan2<<<1, 512, 0, stream>>>(cnt, base, row_ptr);
    k_pscatter<<<NB1, 256, 0, stream>>>(row, col, val, blkhist, base, part);
    k_sort<<<NT, 256, 0, stream>>>(part, cnt, base, row_ptr, csr);

    // layer 1
    k_gemm1<<<(N_NODES + 63) / 64, 256, 0, stream>>>(x, W1, sup);
    k_spmm1<<<(N_NODES * 2 + 255) / 256, 256, 0, stream>>>(row_ptr, csr, sup, b1, h1);
    // layer 2 fused (128 rows/block)
    k_l2fused<<<(N_NODES + 127) / 128, 256, 0, stream>>>(row_ptr, csr, h1, W2, b2, h2);
    // layer 3 fused + pool partials (80 rows/block)
    k_l3fused<<<GRID3, 256, 0, stream>>>(row_ptr, csr, h2, W3, b3, poolpart);
    // pool reduce + head
    k_preduce<<<64, 256, 0, stream>>>(poolpart, pool);
    k_head<<<1, 64, 0, stream>>>(pool, fc1W, fc1b, fc2W, fc2b, out);
}